// Round 1
// baseline (936.343 us; speedup 1.0000x reference)
//
#include <hip/hip_runtime.h>
#include <hip/hip_bf16.h>

#define NN 50000
#define NE 800000
#define DIN 128
#define FH 128      // per-head features
#define NHEAD 2
#define NPAIR 100000

// ---------------- CSR build ----------------
__global__ void count_kernel(const int* __restrict__ dst, int* __restrict__ off) {
    int e = blockIdx.x * 256 + threadIdx.x;
    if (e < NE) atomicAdd(&off[dst[e] + 1], 1);
}

__global__ __launch_bounds__(1024) void scan_kernel(int* __restrict__ data, int n) {
    __shared__ int tile[1024];
    __shared__ int carrysh;
    int tid = threadIdx.x;
    if (tid == 0) carrysh = 0;
    __syncthreads();
    for (int base = 0; base < n; base += 1024) {
        int i = base + tid;
        int v = (i < n) ? data[i] : 0;
        tile[tid] = v;
        __syncthreads();
        for (int offd = 1; offd < 1024; offd <<= 1) {
            int t = (tid >= offd) ? tile[tid - offd] : 0;
            __syncthreads();
            tile[tid] += t;
            __syncthreads();
        }
        int outv = tile[tid] + carrysh;
        if (i < n) data[i] = outv;
        __syncthreads();                 // everyone read carrysh before update
        if (tid == 1023) carrysh = outv;
        __syncthreads();
    }
}

__global__ void fill_kernel(const int* __restrict__ dst, const int* __restrict__ off,
                            int* __restrict__ cursor, int* __restrict__ elist) {
    int e = blockIdx.x * 256 + threadIdx.x;
    if (e < NE) {
        int d = dst[e];
        int pos = off[d] + atomicAdd(&cursor[d], 1);
        elist[pos] = e;
    }
}

// ---------------- GEMM: C[nrows,256] = A[nrows,128] @ W[128,256] ----------------
__global__ __launch_bounds__(256) void gemm_feat(const float* __restrict__ A,
                                                 const float* __restrict__ W,
                                                 float* __restrict__ C, int nrows) {
    __shared__ float As[64][132];   // pad 132: bank-conflict-free r-stride reads
    int rbase = blockIdx.x * 64;
    int cbase = blockIdx.y * 64;
    int tid = threadIdx.x;
    for (int t = tid; t < 64 * 32; t += 256) {
        int r = t >> 5, c4 = (t & 31) << 2;
        int gr = rbase + r;
        float4 v = make_float4(0.f, 0.f, 0.f, 0.f);
        if (gr < nrows) v = *(const float4*)&A[gr * 128 + c4];
        As[r][c4 + 0] = v.x; As[r][c4 + 1] = v.y; As[r][c4 + 2] = v.z; As[r][c4 + 3] = v.w;
    }
    __syncthreads();
    int c4 = (tid & 15) << 2;   // 0..60
    int rowg = tid >> 4;        // 0..15
    float acc[4][4] = {};
    for (int k = 0; k < 128; ++k) {
        float4 w = *(const float4*)&W[k * 256 + cbase + c4];
        #pragma unroll
        for (int i = 0; i < 4; ++i) {
            float a = As[rowg + 16 * i][k];
            acc[i][0] += a * w.x; acc[i][1] += a * w.y;
            acc[i][2] += a * w.z; acc[i][3] += a * w.w;
        }
    }
    #pragma unroll
    for (int i = 0; i < 4; ++i) {
        int gr = rbase + rowg + 16 * i;
        if (gr < nrows) {
            float4 o = make_float4(acc[i][0], acc[i][1], acc[i][2], acc[i][3]);
            *(float4*)&C[gr * 256 + cbase + c4] = o;
        }
    }
}

// ---------------- attention coefficients el/er [N,2] ----------------
__global__ __launch_bounds__(256) void attn_coef(const float* __restrict__ feat,
                                                 const float* __restrict__ al,
                                                 const float* __restrict__ ar,
                                                 float* __restrict__ el, float* __restrict__ er) {
    int n = blockIdx.x;
    int tid = threadIdx.x;
    float f = feat[n * 256 + tid];
    float pl = f * al[tid];
    float pr = f * ar[tid];
    #pragma unroll
    for (int m = 1; m < 64; m <<= 1) { pl += __shfl_xor(pl, m); pr += __shfl_xor(pr, m); }
    __shared__ float redl[4], redr[4];
    int wave = tid >> 6;
    if ((tid & 63) == 0) { redl[wave] = pl; redr[wave] = pr; }
    __syncthreads();
    if (tid == 0)   { el[n * 2 + 0] = redl[0] + redl[1]; er[n * 2 + 0] = redr[0] + redr[1]; }
    if (tid == 128) { el[n * 2 + 1] = redl[2] + redl[3]; er[n * 2 + 1] = redr[2] + redr[3]; }
}

// ---------------- per-dst softmax + aggregation + relu + head-mean ----------------
__global__ __launch_bounds__(256) void aggregate(const float* __restrict__ feat,
                                                 const int* __restrict__ off,
                                                 const int* __restrict__ elist,
                                                 const int* __restrict__ srcv,
                                                 const float* __restrict__ el,
                                                 const float* __restrict__ er,
                                                 float* __restrict__ hout) {
    int v = blockIdx.x;
    int s = off[v], e_end = off[v + 1];
    int deg = e_end - s;
    int tid = threadIdx.x;
    if (deg == 0) {
        if (tid < 32) *(float4*)&hout[v * 128 + tid * 4] = make_float4(0.f, 0.f, 0.f, 0.f);
        return;
    }
    float er0 = er[v * 2 + 0], er1 = er[v * 2 + 1];
    // pass 1: segment max per head
    float m0 = -1e30f, m1 = -1e30f;
    for (int idx = s + tid; idx < e_end; idx += 256) {
        int u = srcv[elist[idx]];
        float a0 = el[u * 2 + 0] + er0; a0 = a0 > 0.f ? a0 : 0.2f * a0;
        float a1 = el[u * 2 + 1] + er1; a1 = a1 > 0.f ? a1 : 0.2f * a1;
        m0 = fmaxf(m0, a0); m1 = fmaxf(m1, a1);
    }
    #pragma unroll
    for (int m = 1; m < 64; m <<= 1) {
        m0 = fmaxf(m0, __shfl_xor(m0, m));
        m1 = fmaxf(m1, __shfl_xor(m1, m));
    }
    __shared__ float redm[4][2];
    int wave = tid >> 6;
    if ((tid & 63) == 0) { redm[wave][0] = m0; redm[wave][1] = m1; }
    __syncthreads();
    m0 = fmaxf(fmaxf(redm[0][0], redm[1][0]), fmaxf(redm[2][0], redm[3][0]));
    m1 = fmaxf(fmaxf(redm[0][1], redm[1][1]), fmaxf(redm[2][1], redm[3][1]));

    // pass 2: chunks of 64 edges; wave0 computes exp weights, all threads accumulate
    __shared__ float wsh[64][2];
    __shared__ int ush[64];
    __shared__ float dsh[2];
    float dsum0 = 0.f, dsum1 = 0.f;
    float acc = 0.f;
    int h = tid >> 7, f = tid & 127;
    for (int cb = 0; cb < deg; cb += 64) {
        int cn = min(64, deg - cb);
        if (tid < cn) {
            int u = srcv[elist[s + cb + tid]];
            float a0 = el[u * 2 + 0] + er0; a0 = a0 > 0.f ? a0 : 0.2f * a0;
            float a1 = el[u * 2 + 1] + er1; a1 = a1 > 0.f ? a1 : 0.2f * a1;
            float w0 = __expf(a0 - m0), w1v = __expf(a1 - m1);
            wsh[tid][0] = w0; wsh[tid][1] = w1v; ush[tid] = u;
            dsum0 += w0; dsum1 += w1v;
        }
        __syncthreads();
        for (int k = 0; k < cn; ++k) {
            acc += wsh[k][h] * feat[ush[k] * 256 + h * 128 + f];
        }
        __syncthreads();
    }
    if (tid < 64) {
        #pragma unroll
        for (int m = 1; m < 64; m <<= 1) {
            dsum0 += __shfl_xor(dsum0, m);
            dsum1 += __shfl_xor(dsum1, m);
        }
        if (tid == 0) { dsh[0] = dsum0; dsh[1] = dsum1; }
    }
    __syncthreads();
    float o = acc / (dsh[h] + 1e-9f);
    o = fmaxf(o, 0.f);
    __shared__ float osh[256];
    osh[tid] = o;
    __syncthreads();
    if (tid < 128) hout[v * 128 + tid] = 0.5f * (osh[tid] + osh[tid + 128]);
}

// ---------------- fused pair MLP ----------------
__global__ __launch_bounds__(256) void mlp_kernel(const float* __restrict__ hf,
                                                  const int* __restrict__ x1,
                                                  const int* __restrict__ x2,
                                                  const float* __restrict__ w1,
                                                  const float* __restrict__ b1,
                                                  const float* __restrict__ w2,
                                                  const float* __restrict__ b2,
                                                  float* __restrict__ out) {
    __shared__ float h1s[64][128];
    __shared__ float h2s[64][128];
    int pbase = blockIdx.x * 64;
    int tid = threadIdx.x;
    for (int t = tid; t < 64 * 32; t += 256) {
        int p = t >> 5, c4 = (t & 31) << 2;
        int gp = pbase + p;
        float4 v1 = make_float4(0.f, 0.f, 0.f, 0.f), v2 = v1;
        if (gp < NPAIR) {
            int i1 = x1[gp], i2 = x2[gp];
            v1 = *(const float4*)&hf[i1 * 128 + c4];
            v2 = *(const float4*)&hf[i2 * 128 + c4];
        }
        *(float4*)&h1s[p][c4] = v1;
        *(float4*)&h2s[p][c4] = v2;
    }
    __syncthreads();
    int c4 = (tid & 31) << 2;   // 0..124 (output col group)
    int pg = tid >> 5;          // 0..7  (pair group)
    float acc[8][4] = {};
    for (int k = 0; k < 128; ++k) {
        float4 w = *(const float4*)&w1[k * 128 + c4];
        #pragma unroll
        for (int i = 0; i < 8; ++i) {
            float a = h1s[pg + 8 * i][k];
            acc[i][0] += a * w.x; acc[i][1] += a * w.y;
            acc[i][2] += a * w.z; acc[i][3] += a * w.w;
        }
    }
    for (int k = 0; k < 128; ++k) {
        float4 w = *(const float4*)&w1[(128 + k) * 128 + c4];
        #pragma unroll
        for (int i = 0; i < 8; ++i) {
            float a = h2s[pg + 8 * i][k];
            acc[i][0] += a * w.x; acc[i][1] += a * w.y;
            acc[i][2] += a * w.z; acc[i][3] += a * w.w;
        }
    }
    for (int k = 0; k < 128; ++k) {
        float4 w = *(const float4*)&w1[(256 + k) * 128 + c4];
        #pragma unroll
        for (int i = 0; i < 8; ++i) {
            float a = fabsf(h1s[pg + 8 * i][k] - h2s[pg + 8 * i][k]);
            acc[i][0] += a * w.x; acc[i][1] += a * w.y;
            acc[i][2] += a * w.z; acc[i][3] += a * w.w;
        }
    }
    float4 b = *(const float4*)&b1[c4];
    float w20[4], w21[4];
    #pragma unroll
    for (int j = 0; j < 4; ++j) { w20[j] = w2[(c4 + j) * 2 + 0]; w21[j] = w2[(c4 + j) * 2 + 1]; }
    float bb0 = b2[0], bb1 = b2[1];
    #pragma unroll
    for (int i = 0; i < 8; ++i) {
        float z0 = fmaxf(acc[i][0] + b.x, 0.f);
        float z1 = fmaxf(acc[i][1] + b.y, 0.f);
        float z2 = fmaxf(acc[i][2] + b.z, 0.f);
        float z3 = fmaxf(acc[i][3] + b.w, 0.f);
        float p0 = z0 * w20[0] + z1 * w20[1] + z2 * w20[2] + z3 * w20[3];
        float p1 = z0 * w21[0] + z1 * w21[1] + z2 * w21[2] + z3 * w21[3];
        #pragma unroll
        for (int m = 1; m < 32; m <<= 1) { p0 += __shfl_xor(p0, m); p1 += __shfl_xor(p1, m); }
        int gp = pbase + pg + 8 * i;
        if ((tid & 31) == 0 && gp < NPAIR) {
            out[gp * 2 + 0] = p0 + bb0;
            out[gp * 2 + 1] = p1 + bb1;
        }
    }
}

extern "C" void kernel_launch(void* const* d_in, const int* in_sizes, int n_in,
                              void* d_out, int out_size, void* d_ws, size_t ws_size,
                              hipStream_t stream) {
    const int*   src = (const int*)d_in[0];
    const int*   dst = (const int*)d_in[1];
    const float* h   = (const float*)d_in[2];
    const int*   x1  = (const int*)d_in[3];
    const int*   x2  = (const int*)d_in[4];
    const float* W0  = (const float*)d_in[5];
    const float* al0 = (const float*)d_in[6];
    const float* ar0 = (const float*)d_in[7];
    const float* W1  = (const float*)d_in[8];
    const float* al1 = (const float*)d_in[9];
    const float* ar1 = (const float*)d_in[10];
    const float* w1  = (const float*)d_in[11];
    const float* b1  = (const float*)d_in[12];
    const float* w2  = (const float*)d_in[13];
    const float* b2  = (const float*)d_in[14];
    float* out = (float*)d_out;

    char* ws = (char*)d_ws;
    size_t o = 0;
    auto alloc = [&](size_t bytes) { size_t r = o; o = (o + bytes + 255) & ~255UL; return r; };
    int*   off    = (int*)(ws + alloc((NN + 1) * sizeof(int)));
    int*   cursor = (int*)(ws + alloc(NN * sizeof(int)));
    int*   elist  = (int*)(ws + alloc(NE * sizeof(int)));
    float* el     = (float*)(ws + alloc(NN * 2 * sizeof(float)));
    float* er     = (float*)(ws + alloc(NN * 2 * sizeof(float)));
    float* feat   = (float*)(ws + alloc((size_t)NN * 256 * sizeof(float)));
    float* hb0    = (float*)(ws + alloc((size_t)NN * 128 * sizeof(float)));
    float* hb1    = (float*)(ws + alloc((size_t)NN * 128 * sizeof(float)));

    hipMemsetAsync(off, 0, (NN + 1) * sizeof(int), stream);
    hipMemsetAsync(cursor, 0, NN * sizeof(int), stream);

    int eblocks = (NE + 255) / 256;
    count_kernel<<<eblocks, 256, 0, stream>>>(dst, off);
    scan_kernel<<<1, 1024, 0, stream>>>(off, NN + 1);
    fill_kernel<<<eblocks, 256, 0, stream>>>(dst, off, cursor, elist);

    dim3 ggrid((NN + 63) / 64, 4);
    // layer 0
    gemm_feat<<<ggrid, 256, 0, stream>>>(h, W0, feat, NN);
    attn_coef<<<NN, 256, 0, stream>>>(feat, al0, ar0, el, er);
    aggregate<<<NN, 256, 0, stream>>>(feat, off, elist, src, el, er, hb0);
    // layer 1
    gemm_feat<<<ggrid, 256, 0, stream>>>(hb0, W1, feat, NN);
    attn_coef<<<NN, 256, 0, stream>>>(feat, al1, ar1, el, er);
    aggregate<<<NN, 256, 0, stream>>>(feat, off, elist, src, el, er, hb1);
    // pair MLP
    mlp_kernel<<<(NPAIR + 63) / 64, 256, 0, stream>>>(hb1, x1, x2, w1, b1, w2, b2, out);
}

// Round 3
// 782.986 us; speedup vs baseline: 1.1959x; 1.1959x over previous
//
#include <hip/hip_runtime.h>
#include <hip/hip_bf16.h>

#define NN 50000
#define NE 800000
#define NPAIR 100000

// ---------------- CSR build ----------------
__global__ __launch_bounds__(256) void count_kernel(const int* __restrict__ dst, int* __restrict__ off) {
    int e = blockIdx.x * 256 + threadIdx.x;
    if (e < NE) atomicAdd(&off[dst[e] + 1], 1);
}

// inclusive scan of data[0..n), 256 per block; block sums to bsums
__global__ __launch_bounds__(256) void scan1(int* __restrict__ data, int* __restrict__ bsums, int n) {
    int tid = threadIdx.x;
    int i = blockIdx.x * 256 + tid;
    int v = (i < n) ? data[i] : 0;
    #pragma unroll
    for (int d = 1; d < 64; d <<= 1) {
        int t = __shfl_up(v, d);
        if ((tid & 63) >= d) v += t;
    }
    __shared__ int ws[4];
    if ((tid & 63) == 63) ws[tid >> 6] = v;
    __syncthreads();
    int w = tid >> 6;
    if (w > 0) v += ws[0];
    if (w > 1) v += ws[1];
    if (w > 2) v += ws[2];
    if (i < n) data[i] = v;
    if (tid == 255) bsums[blockIdx.x] = v;
}

__global__ __launch_bounds__(256) void scan2(int* __restrict__ bsums, int nb) {
    int tid = threadIdx.x;
    int v = (tid < nb) ? bsums[tid] : 0;
    #pragma unroll
    for (int d = 1; d < 64; d <<= 1) {
        int t = __shfl_up(v, d);
        if ((tid & 63) >= d) v += t;
    }
    __shared__ int ws[4];
    if ((tid & 63) == 63) ws[tid >> 6] = v;
    __syncthreads();
    int w = tid >> 6;
    if (w > 0) v += ws[0];
    if (w > 1) v += ws[1];
    if (w > 2) v += ws[2];
    if (tid < nb) bsums[tid] = v;
}

__global__ __launch_bounds__(256) void scan3(int* __restrict__ data, const int* __restrict__ bsums, int n) {
    int i = blockIdx.x * 256 + threadIdx.x;
    if (i < n && blockIdx.x > 0) data[i] += bsums[blockIdx.x - 1];
}

__global__ __launch_bounds__(256) void fill_kernel(const int* __restrict__ dst, const int* __restrict__ off,
                                                   int* __restrict__ cursor, int* __restrict__ elist) {
    int e = blockIdx.x * 256 + threadIdx.x;
    if (e < NE) {
        int d = dst[e];
        int pos = off[d] + atomicAdd(&cursor[d], 1);
        elist[pos] = e;
    }
}

// ---- fused GEMM + attention-coef: C[nrows,256] = A[nrows,128]@W[128,256]; el/er per head ----
// grid = (ceil(nrows/64), 2); blockIdx.y = head; tile 64 rows x 128 cols (one full head)
__global__ __launch_bounds__(256) void gemm_fused(const float* __restrict__ A,
                                                  const float* __restrict__ W,
                                                  const float* __restrict__ al,
                                                  const float* __restrict__ ar,
                                                  float* __restrict__ C,
                                                  float* __restrict__ att, int nrows) {
    __shared__ float As[64][133];   // pad 133: rows 16 apart land 16 banks apart
    int rbase = blockIdx.x * 64;
    int head = blockIdx.y;
    int cbase = head * 128;
    int tid = threadIdx.x;
    for (int t = tid; t < 64 * 32; t += 256) {
        int r = t >> 5, c4 = (t & 31) << 2;
        int gr = rbase + r;
        float4 v = make_float4(0.f, 0.f, 0.f, 0.f);
        if (gr < nrows) v = *(const float4*)&A[gr * 128 + c4];
        As[r][c4 + 0] = v.x; As[r][c4 + 1] = v.y; As[r][c4 + 2] = v.z; As[r][c4 + 3] = v.w;
    }
    __syncthreads();
    int cg = tid & 15;          // 16 col groups x 8 cols = 128
    int c8 = cg << 3;
    int rg = tid >> 4;          // 16 row groups x 4 rows = 64
    float acc[4][8] = {};
    #pragma unroll 2
    for (int k = 0; k < 128; ++k) {
        float4 w0 = *(const float4*)&W[k * 256 + cbase + c8];
        float4 w1 = *(const float4*)&W[k * 256 + cbase + c8 + 4];
        float a[4];
        #pragma unroll
        for (int i = 0; i < 4; ++i) a[i] = As[rg + 16 * i][k];
        #pragma unroll
        for (int i = 0; i < 4; ++i) {
            acc[i][0] += a[i] * w0.x; acc[i][1] += a[i] * w0.y;
            acc[i][2] += a[i] * w0.z; acc[i][3] += a[i] * w0.w;
            acc[i][4] += a[i] * w1.x; acc[i][5] += a[i] * w1.y;
            acc[i][6] += a[i] * w1.z; acc[i][7] += a[i] * w1.w;
        }
    }
    float4 al0 = *(const float4*)&al[cbase + c8];
    float4 al1 = *(const float4*)&al[cbase + c8 + 4];
    float4 ar0 = *(const float4*)&ar[cbase + c8];
    float4 ar1 = *(const float4*)&ar[cbase + c8 + 4];
    #pragma unroll
    for (int i = 0; i < 4; ++i) {
        int gr = rbase + rg + 16 * i;
        float pl = acc[i][0] * al0.x + acc[i][1] * al0.y + acc[i][2] * al0.z + acc[i][3] * al0.w
                 + acc[i][4] * al1.x + acc[i][5] * al1.y + acc[i][6] * al1.z + acc[i][7] * al1.w;
        float pr = acc[i][0] * ar0.x + acc[i][1] * ar0.y + acc[i][2] * ar0.z + acc[i][3] * ar0.w
                 + acc[i][4] * ar1.x + acc[i][5] * ar1.y + acc[i][6] * ar1.z + acc[i][7] * ar1.w;
        #pragma unroll
        for (int m = 1; m < 16; m <<= 1) { pl += __shfl_xor(pl, m); pr += __shfl_xor(pr, m); }
        if (gr < nrows) {
            *(float4*)&C[gr * 256 + cbase + c8] = make_float4(acc[i][0], acc[i][1], acc[i][2], acc[i][3]);
            *(float4*)&C[gr * 256 + cbase + c8 + 4] = make_float4(acc[i][4], acc[i][5], acc[i][6], acc[i][7]);
            if (cg == 0) {
                att[gr * 4 + head] = pl;         // el
                att[gr * 4 + 2 + head] = pr;     // er
            }
        }
    }
}

// ---------------- per-dst softmax + aggregation + relu + head-mean ----------------
__global__ __launch_bounds__(256) void aggregate(const float* __restrict__ feat,
                                                 const int* __restrict__ off,
                                                 const int* __restrict__ elist,
                                                 const int* __restrict__ srcv,
                                                 const float* __restrict__ att,
                                                 float* __restrict__ hout) {
    int v = blockIdx.x;
    int s = off[v], e_end = off[v + 1];
    int deg = e_end - s;
    int tid = threadIdx.x;
    if (deg == 0) {
        if (tid < 32) *(float4*)&hout[v * 128 + tid * 4] = make_float4(0.f, 0.f, 0.f, 0.f);
        return;
    }
    float4 av = ((const float4*)att)[v];
    float er0 = av.z, er1 = av.w;
    int h = tid >> 7, f = tid & 127;
    int foff = h * 128 + f;   // == tid

    __shared__ int ush[256];
    __shared__ float w0sh[256], w1sh[256];
    __shared__ float red[4][4];
    __shared__ float dsh[2];
    __shared__ float osh[256];
    int wave = tid >> 6;

    float acc = 0.f;
    if (deg <= 256) {
        float e0 = -1e30f, e1 = -1e30f;
        int u = 0;
        if (tid < deg) {
            u = srcv[elist[s + tid]];
            float4 au = ((const float4*)att)[u];
            e0 = au.x + er0; e0 = e0 > 0.f ? e0 : 0.2f * e0;
            e1 = au.y + er1; e1 = e1 > 0.f ? e1 : 0.2f * e1;
            ush[tid] = u;
        }
        float m0 = e0, m1 = e1;
        #pragma unroll
        for (int m = 1; m < 64; m <<= 1) {
            m0 = fmaxf(m0, __shfl_xor(m0, m));
            m1 = fmaxf(m1, __shfl_xor(m1, m));
        }
        if ((tid & 63) == 0) { red[wave][0] = m0; red[wave][1] = m1; }
        __syncthreads();
        m0 = fmaxf(fmaxf(red[0][0], red[1][0]), fmaxf(red[2][0], red[3][0]));
        m1 = fmaxf(fmaxf(red[0][1], red[1][1]), fmaxf(red[2][1], red[3][1]));
        float w0 = 0.f, w1 = 0.f;
        if (tid < deg) {
            w0 = __expf(e0 - m0); w1 = __expf(e1 - m1);
            w0sh[tid] = w0; w1sh[tid] = w1;
        }
        float s0 = w0, s1 = w1;
        #pragma unroll
        for (int m = 1; m < 64; m <<= 1) { s0 += __shfl_xor(s0, m); s1 += __shfl_xor(s1, m); }
        __syncthreads();   // red reuse
        if ((tid & 63) == 0) { red[wave][2] = s0; red[wave][3] = s1; }
        __syncthreads();   // publishes w0sh/w1sh/ush too
        if (tid == 0) {
            dsh[0] = red[0][2] + red[1][2] + red[2][2] + red[3][2];
            dsh[1] = red[0][3] + red[1][3] + red[2][3] + red[3][3];
        }
        __syncthreads();
        const float* wh = h ? w1sh : w0sh;
        int k = 0;
        for (; k + 4 <= deg; k += 4) {
            int u0 = ush[k], u1 = ush[k + 1], u2 = ush[k + 2], u3 = ush[k + 3];
            float q0 = wh[k], q1 = wh[k + 1], q2 = wh[k + 2], q3 = wh[k + 3];
            float f0 = feat[u0 * 256 + foff];
            float f1 = feat[u1 * 256 + foff];
            float f2 = feat[u2 * 256 + foff];
            float f3 = feat[u3 * 256 + foff];
            acc += q0 * f0 + q1 * f1 + q2 * f2 + q3 * f3;
        }
        for (; k < deg; ++k) acc += wh[k] * feat[ush[k] * 256 + foff];
    } else {
        // general chunked path (deg > 256) — rare/never for this graph
        float m0 = -1e30f, m1 = -1e30f;
        for (int idx = s + tid; idx < e_end; idx += 256) {
            int u = srcv[elist[idx]];
            float4 au = ((const float4*)att)[u];
            float a0 = au.x + er0; a0 = a0 > 0.f ? a0 : 0.2f * a0;
            float a1 = au.y + er1; a1 = a1 > 0.f ? a1 : 0.2f * a1;
            m0 = fmaxf(m0, a0); m1 = fmaxf(m1, a1);
        }
        #pragma unroll
        for (int m = 1; m < 64; m <<= 1) {
            m0 = fmaxf(m0, __shfl_xor(m0, m));
            m1 = fmaxf(m1, __shfl_xor(m1, m));
        }
        if ((tid & 63) == 0) { red[wave][0] = m0; red[wave][1] = m1; }
        __syncthreads();
        m0 = fmaxf(fmaxf(red[0][0], red[1][0]), fmaxf(red[2][0], red[3][0]));
        m1 = fmaxf(fmaxf(red[0][1], red[1][1]), fmaxf(red[2][1], red[3][1]));
        float dsum0 = 0.f, dsum1 = 0.f;
        const float* wh = h ? w1sh : w0sh;
        for (int cb = 0; cb < deg; cb += 256) {
            int cn = min(256, deg - cb);
            __syncthreads();
            if (tid < cn) {
                int u = srcv[elist[s + cb + tid]];
                float4 au = ((const float4*)att)[u];
                float a0 = au.x + er0; a0 = a0 > 0.f ? a0 : 0.2f * a0;
                float a1 = au.y + er1; a1 = a1 > 0.f ? a1 : 0.2f * a1;
                float w0 = __expf(a0 - m0), w1 = __expf(a1 - m1);
                w0sh[tid] = w0; w1sh[tid] = w1; ush[tid] = u;
                dsum0 += w0; dsum1 += w1;
            }
            __syncthreads();
            for (int k = 0; k < cn; ++k) acc += wh[k] * feat[ush[k] * 256 + foff];
        }
        #pragma unroll
        for (int m = 1; m < 64; m <<= 1) { dsum0 += __shfl_xor(dsum0, m); dsum1 += __shfl_xor(dsum1, m); }
        __syncthreads();
        if ((tid & 63) == 0) { red[wave][2] = dsum0; red[wave][3] = dsum1; }
        __syncthreads();
        if (tid == 0) {
            dsh[0] = red[0][2] + red[1][2] + red[2][2] + red[3][2];
            dsh[1] = red[0][3] + red[1][3] + red[2][3] + red[3][3];
        }
        __syncthreads();
    }
    float o = acc / (dsh[h] + 1e-9f);
    o = fmaxf(o, 0.f);
    osh[tid] = o;
    __syncthreads();
    if (tid < 128) hout[v * 128 + tid] = 0.5f * (osh[tid] + osh[tid + 128]);
}

// ---------------- fused pair MLP ----------------
__global__ __launch_bounds__(256) void mlp_kernel(const float* __restrict__ hf,
                                                  const int* __restrict__ x1,
                                                  const int* __restrict__ x2,
                                                  const float* __restrict__ w1,
                                                  const float* __restrict__ b1,
                                                  const float* __restrict__ w2,
                                                  const float* __restrict__ b2,
                                                  float* __restrict__ out) {
    // XOR-swizzled LDS: col index ^= ((row>>4)&3)<<2  -> the 4 rows a thread reads
    // per k (stride 16) land in 4 distinct banks. float4-alignment preserved.
    __shared__ float h1s[64][128];
    __shared__ float h2s[64][128];
    int pbase = blockIdx.x * 64;
    int tid = threadIdx.x;
    for (int t = tid; t < 64 * 32; t += 256) {
        int p = t >> 5, c4 = (t & 31) << 2;
        int sw = ((p >> 4) & 3) << 2;
        int gp = pbase + p;
        float4 v1 = make_float4(0.f, 0.f, 0.f, 0.f), v2 = v1;
        if (gp < NPAIR) {
            int i1 = x1[gp], i2 = x2[gp];
            v1 = *(const float4*)&hf[i1 * 128 + c4];
            v2 = *(const float4*)&hf[i2 * 128 + c4];
        }
        *(float4*)&h1s[p][c4 ^ sw] = v1;
        *(float4*)&h2s[p][c4 ^ sw] = v2;
    }
    __syncthreads();
    int cg = tid & 15;          // 16 col groups x 8 = 128 cols
    int c8 = cg << 3;
    int rg = tid >> 4;          // 16 row groups x 4 = 64 pairs
    float acc[4][8] = {};
    #pragma unroll 2
    for (int k = 0; k < 128; ++k) {
        float a1[4], a2[4], ad[4];
        #pragma unroll
        for (int i = 0; i < 4; ++i) {
            a1[i] = h1s[rg + 16 * i][k ^ (i << 2)];
            a2[i] = h2s[rg + 16 * i][k ^ (i << 2)];
            ad[i] = fabsf(a1[i] - a2[i]);
        }
        float4 wA0 = *(const float4*)&w1[k * 128 + c8];
        float4 wA1 = *(const float4*)&w1[k * 128 + c8 + 4];
        float4 wB0 = *(const float4*)&w1[(128 + k) * 128 + c8];
        float4 wB1 = *(const float4*)&w1[(128 + k) * 128 + c8 + 4];
        float4 wC0 = *(const float4*)&w1[(256 + k) * 128 + c8];
        float4 wC1 = *(const float4*)&w1[(256 + k) * 128 + c8 + 4];
        #pragma unroll
        for (int i = 0; i < 4; ++i) {
            acc[i][0] += a1[i] * wA0.x + a2[i] * wB0.x + ad[i] * wC0.x;
            acc[i][1] += a1[i] * wA0.y + a2[i] * wB0.y + ad[i] * wC0.y;
            acc[i][2] += a1[i] * wA0.z + a2[i] * wB0.z + ad[i] * wC0.z;
            acc[i][3] += a1[i] * wA0.w + a2[i] * wB0.w + ad[i] * wC0.w;
            acc[i][4] += a1[i] * wA1.x + a2[i] * wB1.x + ad[i] * wC1.x;
            acc[i][5] += a1[i] * wA1.y + a2[i] * wB1.y + ad[i] * wC1.y;
            acc[i][6] += a1[i] * wA1.z + a2[i] * wB1.z + ad[i] * wC1.z;
            acc[i][7] += a1[i] * wA1.w + a2[i] * wB1.w + ad[i] * wC1.w;
        }
    }
    float4 bv0 = *(const float4*)&b1[c8];
    float4 bv1 = *(const float4*)&b1[c8 + 4];
    float bb[8] = { bv0.x, bv0.y, bv0.z, bv0.w, bv1.x, bv1.y, bv1.z, bv1.w };
    float w20[8], w21[8];
    #pragma unroll
    for (int j = 0; j < 8; ++j) { w20[j] = w2[(c8 + j) * 2 + 0]; w21[j] = w2[(c8 + j) * 2 + 1]; }
    float ob0 = b2[0], ob1 = b2[1];
    #pragma unroll
    for (int i = 0; i < 4; ++i) {
        float p0 = 0.f, p1 = 0.f;
        #pragma unroll
        for (int j = 0; j < 8; ++j) {
            float z = fmaxf(acc[i][j] + bb[j], 0.f);
            p0 += z * w20[j]; p1 += z * w21[j];
        }
        #pragma unroll
        for (int m = 1; m < 16; m <<= 1) { p0 += __shfl_xor(p0, m); p1 += __shfl_xor(p1, m); }
        int gp = pbase + rg + 16 * i;
        if (cg == 0 && gp < NPAIR) {
            out[gp * 2 + 0] = p0 + ob0;
            out[gp * 2 + 1] = p1 + ob1;
        }
    }
}

extern "C" void kernel_launch(void* const* d_in, const int* in_sizes, int n_in,
                              void* d_out, int out_size, void* d_ws, size_t ws_size,
                              hipStream_t stream) {
    const int*   src = (const int*)d_in[0];
    const int*   dst = (const int*)d_in[1];
    const float* h   = (const float*)d_in[2];
    const int*   x1  = (const int*)d_in[3];
    const int*   x2  = (const int*)d_in[4];
    const float* W0  = (const float*)d_in[5];
    const float* al0 = (const float*)d_in[6];
    const float* ar0 = (const float*)d_in[7];
    const float* W1  = (const float*)d_in[8];
    const float* al1 = (const float*)d_in[9];
    const float* ar1 = (const float*)d_in[10];
    const float* w1  = (const float*)d_in[11];
    const float* b1  = (const float*)d_in[12];
    const float* w2  = (const float*)d_in[13];
    const float* b2  = (const float*)d_in[14];
    float* out = (float*)d_out;

    char* ws = (char*)d_ws;
    size_t o = 0;
    auto alloc = [&](size_t bytes) { size_t r = o; o = (o + bytes + 255) & ~255UL; return r; };
    int*   off    = (int*)(ws + alloc((NN + 1) * sizeof(int)));
    int*   cursor = (int*)(ws + alloc(NN * sizeof(int)));
    int*   bsums  = (int*)(ws + alloc(256 * sizeof(int)));
    int*   elist  = (int*)(ws + alloc(NE * sizeof(int)));
    float* att    = (float*)(ws + alloc((size_t)NN * 4 * sizeof(float)));
    float* feat   = (float*)(ws + alloc((size_t)NN * 256 * sizeof(float)));
    float* hb0    = (float*)(ws + alloc((size_t)NN * 128 * sizeof(float)));
    float* hb1    = (float*)(ws + alloc((size_t)NN * 128 * sizeof(float)));

    hipMemsetAsync(off, 0, (NN + 1) * sizeof(int), stream);
    hipMemsetAsync(cursor, 0, NN * sizeof(int), stream);

    int eblocks = (NE + 255) / 256;
    int nscan = NN + 1;
    int nb = (nscan + 255) / 256;   // 196
    count_kernel<<<eblocks, 256, 0, stream>>>(dst, off);
    scan1<<<nb, 256, 0, stream>>>(off, bsums, nscan);
    scan2<<<1, 256, 0, stream>>>(bsums, nb);
    scan3<<<nb, 256, 0, stream>>>(off, bsums, nscan);
    fill_kernel<<<eblocks, 256, 0, stream>>>(dst, off, cursor, elist);

    dim3 ggrid((NN + 63) / 64, 2);
    // layer 0
    gemm_fused<<<ggrid, 256, 0, stream>>>(h, W0, al0, ar0, feat, att, NN);
    aggregate<<<NN, 256, 0, stream>>>(feat, off, elist, src, att, hb0);
    // layer 1
    gemm_fused<<<ggrid, 256, 0, stream>>>(hb0, W1, al1, ar1, feat, att, NN);
    aggregate<<<NN, 256, 0, stream>>>(feat, off, elist, src, att, hb1);
    // pair MLP
    mlp_kernel<<<(NPAIR + 63) / 64, 256, 0, stream>>>(hb1, x1, x2, w1, b1, w2, b2, out);
}

// Round 4
// 670.338 us; speedup vs baseline: 1.3968x; 1.1680x over previous
//
#include <hip/hip_runtime.h>
#include <hip/hip_bf16.h>

#define NN 50000
#define NE 800000
#define NPAIR 100000

typedef unsigned int u32;
typedef unsigned short u16;

__device__ __forceinline__ float bflo(u32 u) { return __uint_as_float(u << 16); }
__device__ __forceinline__ float bfhi(u32 u) { return __uint_as_float(u & 0xffff0000u); }
__device__ __forceinline__ u32 bfround(float f) {
    u32 u = __float_as_uint(f);
    return (u + 0x7fffu + ((u >> 16) & 1u)) >> 16;
}
__device__ __forceinline__ u32 packbf(float a, float b) {
    return bfround(a) | (bfround(b) << 16);
}

// ---------------- CSR build ----------------
__global__ __launch_bounds__(256) void count_kernel(const int* __restrict__ dst, int* __restrict__ off) {
    int e = blockIdx.x * 256 + threadIdx.x;
    if (e < NE) atomicAdd(&off[dst[e] + 1], 1);
}

__global__ __launch_bounds__(256) void scan1(int* __restrict__ data, int* __restrict__ bsums, int n) {
    int tid = threadIdx.x;
    int i = blockIdx.x * 256 + tid;
    int v = (i < n) ? data[i] : 0;
    #pragma unroll
    for (int d = 1; d < 64; d <<= 1) {
        int t = __shfl_up(v, d);
        if ((tid & 63) >= d) v += t;
    }
    __shared__ int ws[4];
    if ((tid & 63) == 63) ws[tid >> 6] = v;
    __syncthreads();
    int w = tid >> 6;
    if (w > 0) v += ws[0];
    if (w > 1) v += ws[1];
    if (w > 2) v += ws[2];
    if (i < n) data[i] = v;
    if (tid == 255) bsums[blockIdx.x] = v;
}

__global__ __launch_bounds__(256) void scan2(int* __restrict__ bsums, int nb) {
    int tid = threadIdx.x;
    int v = (tid < nb) ? bsums[tid] : 0;
    #pragma unroll
    for (int d = 1; d < 64; d <<= 1) {
        int t = __shfl_up(v, d);
        if ((tid & 63) >= d) v += t;
    }
    __shared__ int ws[4];
    if ((tid & 63) == 63) ws[tid >> 6] = v;
    __syncthreads();
    int w = tid >> 6;
    if (w > 0) v += ws[0];
    if (w > 1) v += ws[1];
    if (w > 2) v += ws[2];
    if (tid < nb) bsums[tid] = v;
}

__global__ __launch_bounds__(256) void scan3(int* __restrict__ data, const int* __restrict__ bsums, int n) {
    int i = blockIdx.x * 256 + threadIdx.x;
    if (i < n && blockIdx.x > 0) data[i] += bsums[blockIdx.x - 1];
}

__global__ __launch_bounds__(256) void fill_kernel(const int* __restrict__ dst, const int* __restrict__ off,
                                                   int* __restrict__ cursor, int* __restrict__ elist) {
    int e = blockIdx.x * 256 + threadIdx.x;
    if (e < NE) {
        int d = dst[e];
        int pos = off[d] + atomicAdd(&cursor[d], 1);
        elist[pos] = e;
    }
}

// ---- fused GEMM + attention-coef: C(bf16)[nrows,256] = A[nrows,128]@W[128,256] ----
// grid = (ceil(nrows/64), 2); blockIdx.y = head; tile 64 rows x 128 cols (one full head)
// el/er computed from fp32 accumulators (full precision), C stored bf16.
template<bool ABF16>
__global__ __launch_bounds__(256) void gemm_fused(const void* __restrict__ Av,
                                                  const float* __restrict__ W,
                                                  const float* __restrict__ al,
                                                  const float* __restrict__ ar,
                                                  u16* __restrict__ C,
                                                  float* __restrict__ att, int nrows) {
    __shared__ float As[64][133];   // pad 133: rows 0..3 -> banks 0,5,10,15 (+k)
    int rbase = blockIdx.x * 64;
    int head = blockIdx.y;
    int cbase = head * 128;
    int tid = threadIdx.x;
    if (ABF16) {
        const u16* A = (const u16*)Av;
        for (int id = tid; id < 64 * 16; id += 256) {
            int r = id >> 4, c8 = (id & 15) << 3;
            int gr = rbase + r;
            uint4 v = make_uint4(0u, 0u, 0u, 0u);
            if (gr < nrows) v = *(const uint4*)&A[gr * 128 + c8];
            As[r][c8 + 0] = bflo(v.x); As[r][c8 + 1] = bfhi(v.x);
            As[r][c8 + 2] = bflo(v.y); As[r][c8 + 3] = bfhi(v.y);
            As[r][c8 + 4] = bflo(v.z); As[r][c8 + 5] = bfhi(v.z);
            As[r][c8 + 6] = bflo(v.w); As[r][c8 + 7] = bfhi(v.w);
        }
    } else {
        const float* A = (const float*)Av;
        for (int t = tid; t < 64 * 32; t += 256) {
            int r = t >> 5, c4 = (t & 31) << 2;
            int gr = rbase + r;
            float4 v = make_float4(0.f, 0.f, 0.f, 0.f);
            if (gr < nrows) v = *(const float4*)&A[gr * 128 + c4];
            As[r][c4 + 0] = v.x; As[r][c4 + 1] = v.y; As[r][c4 + 2] = v.z; As[r][c4 + 3] = v.w;
        }
    }
    __syncthreads();
    int cg = tid & 15;          // 16 col groups x 8 cols = 128
    int c8 = cg << 3;
    int rg = tid >> 4;          // 16 row groups x 4 rows = 64
    float acc[4][8] = {};
    #pragma unroll 2
    for (int k = 0; k < 128; ++k) {
        float4 w0 = *(const float4*)&W[k * 256 + cbase + c8];
        float4 w1 = *(const float4*)&W[k * 256 + cbase + c8 + 4];
        float a[4];
        #pragma unroll
        for (int i = 0; i < 4; ++i) a[i] = As[rg + 16 * i][k];
        #pragma unroll
        for (int i = 0; i < 4; ++i) {
            acc[i][0] += a[i] * w0.x; acc[i][1] += a[i] * w0.y;
            acc[i][2] += a[i] * w0.z; acc[i][3] += a[i] * w0.w;
            acc[i][4] += a[i] * w1.x; acc[i][5] += a[i] * w1.y;
            acc[i][6] += a[i] * w1.z; acc[i][7] += a[i] * w1.w;
        }
    }
    float4 al0 = *(const float4*)&al[cbase + c8];
    float4 al1 = *(const float4*)&al[cbase + c8 + 4];
    float4 ar0 = *(const float4*)&ar[cbase + c8];
    float4 ar1 = *(const float4*)&ar[cbase + c8 + 4];
    u32* Cu = (u32*)C;
    #pragma unroll
    for (int i = 0; i < 4; ++i) {
        int gr = rbase + rg + 16 * i;
        float pl = acc[i][0] * al0.x + acc[i][1] * al0.y + acc[i][2] * al0.z + acc[i][3] * al0.w
                 + acc[i][4] * al1.x + acc[i][5] * al1.y + acc[i][6] * al1.z + acc[i][7] * al1.w;
        float pr = acc[i][0] * ar0.x + acc[i][1] * ar0.y + acc[i][2] * ar0.z + acc[i][3] * ar0.w
                 + acc[i][4] * ar1.x + acc[i][5] * ar1.y + acc[i][6] * ar1.z + acc[i][7] * ar1.w;
        #pragma unroll
        for (int m = 1; m < 16; m <<= 1) { pl += __shfl_xor(pl, m); pr += __shfl_xor(pr, m); }
        if (gr < nrows) {
            uint4 q;
            q.x = packbf(acc[i][0], acc[i][1]);
            q.y = packbf(acc[i][2], acc[i][3]);
            q.z = packbf(acc[i][4], acc[i][5]);
            q.w = packbf(acc[i][6], acc[i][7]);
            *(uint4*)&Cu[gr * 128 + ((cbase + c8) >> 1)] = q;
            if (cg == 0) {
                att[gr * 4 + head] = pl;         // el
                att[gr * 4 + 2 + head] = pr;     // er
            }
        }
    }
}

// ---------------- per-dst softmax + aggregation + relu + head-mean (bf16 feat) ----------------
// 128 threads: lane owns one bfloat162 (2 features) of one head. h = tid>>6.
__global__ __launch_bounds__(128) void aggregate(const u16* __restrict__ feat,
                                                 const int* __restrict__ off,
                                                 const int* __restrict__ elist,
                                                 const int* __restrict__ srcv,
                                                 const float* __restrict__ att,
                                                 u16* __restrict__ hout) {
    int v = blockIdx.x;
    int s = off[v], e_end = off[v + 1];
    int deg = e_end - s;
    int tid = threadIdx.x;
    u32* houtu = (u32*)hout;
    const u32* featu = (const u32*)feat;
    if (deg == 0) {
        if (tid < 64) houtu[v * 64 + tid] = 0u;
        return;
    }
    const float4* att4 = (const float4*)att;
    float4 av = att4[v];
    float er0 = av.z, er1 = av.w;
    int h = tid >> 6;
    int wave = h;

    __shared__ int ush[256];
    __shared__ float w0sh[256], w1sh[256];
    __shared__ float red[2][4];
    __shared__ float dsh[2];
    __shared__ float2 osh[128];

    float accx = 0.f, accy = 0.f;
    const float* wh = h ? w1sh : w0sh;

    if (deg <= 256) {
        float e0a[2], e1a[2];
        float m0 = -1e30f, m1 = -1e30f;
        #pragma unroll
        for (int jj = 0; jj < 2; ++jj) {
            int j = tid + 128 * jj;
            e0a[jj] = -1e30f; e1a[jj] = -1e30f;
            if (j < deg) {
                int u = srcv[elist[s + j]];
                ush[j] = u;
                float4 au = att4[u];
                float a0 = au.x + er0; a0 = a0 > 0.f ? a0 : 0.2f * a0;
                float a1 = au.y + er1; a1 = a1 > 0.f ? a1 : 0.2f * a1;
                e0a[jj] = a0; e1a[jj] = a1;
                m0 = fmaxf(m0, a0); m1 = fmaxf(m1, a1);
            }
        }
        #pragma unroll
        for (int m = 1; m < 64; m <<= 1) {
            m0 = fmaxf(m0, __shfl_xor(m0, m));
            m1 = fmaxf(m1, __shfl_xor(m1, m));
        }
        if ((tid & 63) == 0) { red[wave][0] = m0; red[wave][1] = m1; }
        __syncthreads();
        m0 = fmaxf(red[0][0], red[1][0]);
        m1 = fmaxf(red[0][1], red[1][1]);
        float s0 = 0.f, s1 = 0.f;
        #pragma unroll
        for (int jj = 0; jj < 2; ++jj) {
            int j = tid + 128 * jj;
            if (j < deg) {
                float w0 = __expf(e0a[jj] - m0), w1 = __expf(e1a[jj] - m1);
                w0sh[j] = w0; w1sh[j] = w1;
                s0 += w0; s1 += w1;
            }
        }
        #pragma unroll
        for (int m = 1; m < 64; m <<= 1) { s0 += __shfl_xor(s0, m); s1 += __shfl_xor(s1, m); }
        if ((tid & 63) == 0) { red[wave][2] = s0; red[wave][3] = s1; }
        __syncthreads();   // also publishes ush/w0sh/w1sh
        if (tid == 0) {
            dsh[0] = red[0][2] + red[1][2];
            dsh[1] = red[0][3] + red[1][3];
        }
        __syncthreads();
        int k = 0;
        for (; k + 4 <= deg; k += 4) {
            int u0 = ush[k], u1 = ush[k + 1], u2 = ush[k + 2], u3 = ush[k + 3];
            float q0 = wh[k], q1 = wh[k + 1], q2 = wh[k + 2], q3 = wh[k + 3];
            u32 f0 = featu[u0 * 128 + tid];
            u32 f1 = featu[u1 * 128 + tid];
            u32 f2 = featu[u2 * 128 + tid];
            u32 f3 = featu[u3 * 128 + tid];
            accx += q0 * bflo(f0) + q1 * bflo(f1) + q2 * bflo(f2) + q3 * bflo(f3);
            accy += q0 * bfhi(f0) + q1 * bfhi(f1) + q2 * bfhi(f2) + q3 * bfhi(f3);
        }
        for (; k < deg; ++k) {
            u32 fu = featu[ush[k] * 128 + tid];
            accx += wh[k] * bflo(fu);
            accy += wh[k] * bfhi(fu);
        }
    } else {
        // general chunked path (deg > 256) — essentially never for this graph
        float m0 = -1e30f, m1 = -1e30f;
        for (int idx = s + tid; idx < e_end; idx += 128) {
            int u = srcv[elist[idx]];
            float4 au = att4[u];
            float a0 = au.x + er0; a0 = a0 > 0.f ? a0 : 0.2f * a0;
            float a1 = au.y + er1; a1 = a1 > 0.f ? a1 : 0.2f * a1;
            m0 = fmaxf(m0, a0); m1 = fmaxf(m1, a1);
        }
        #pragma unroll
        for (int m = 1; m < 64; m <<= 1) {
            m0 = fmaxf(m0, __shfl_xor(m0, m));
            m1 = fmaxf(m1, __shfl_xor(m1, m));
        }
        if ((tid & 63) == 0) { red[wave][0] = m0; red[wave][1] = m1; }
        __syncthreads();
        m0 = fmaxf(red[0][0], red[1][0]);
        m1 = fmaxf(red[0][1], red[1][1]);
        float dsum0 = 0.f, dsum1 = 0.f;
        for (int cb = 0; cb < deg; cb += 128) {
            int cn = min(128, deg - cb);
            __syncthreads();
            if (tid < cn) {
                int u = srcv[elist[s + cb + tid]];
                float4 au = att4[u];
                float a0 = au.x + er0; a0 = a0 > 0.f ? a0 : 0.2f * a0;
                float a1 = au.y + er1; a1 = a1 > 0.f ? a1 : 0.2f * a1;
                float w0 = __expf(a0 - m0), w1 = __expf(a1 - m1);
                w0sh[tid] = w0; w1sh[tid] = w1; ush[tid] = u;
                dsum0 += w0; dsum1 += w1;
            }
            __syncthreads();
            for (int k = 0; k < cn; ++k) {
                u32 fu = featu[ush[k] * 128 + tid];
                accx += wh[k] * bflo(fu);
                accy += wh[k] * bfhi(fu);
            }
        }
        #pragma unroll
        for (int m = 1; m < 64; m <<= 1) { dsum0 += __shfl_xor(dsum0, m); dsum1 += __shfl_xor(dsum1, m); }
        __syncthreads();
        if ((tid & 63) == 0) { red[wave][2] = dsum0; red[wave][3] = dsum1; }
        __syncthreads();
        if (tid == 0) {
            dsh[0] = red[0][2] + red[1][2];
            dsh[1] = red[0][3] + red[1][3];
        }
        __syncthreads();
    }
    float d = dsh[h] + 1e-9f;
    float ox = fmaxf(accx / d, 0.f);
    float oy = fmaxf(accy / d, 0.f);
    osh[tid] = make_float2(ox, oy);
    __syncthreads();
    if (tid < 64) {
        float2 a = osh[tid], b = osh[tid + 64];
        houtu[v * 64 + tid] = packbf(0.5f * (a.x + b.x), 0.5f * (a.y + b.y));
    }
}

// ---------------- fused pair MLP (bf16 h gather, fp32 math) ----------------
__global__ __launch_bounds__(256) void mlp_kernel(const u16* __restrict__ hf,
                                                  const int* __restrict__ x1,
                                                  const int* __restrict__ x2,
                                                  const float* __restrict__ w1,
                                                  const float* __restrict__ b1,
                                                  const float* __restrict__ w2,
                                                  const float* __restrict__ b2,
                                                  float* __restrict__ out) {
    // bf16 rows in LDS as u32 pairs [64][64]; swizzle uint-idx ^= (row&3)<<2 at
    // uint4 granularity: the 4 wave-simultaneous rows (rg=0..3) hit distinct
    // bank pairs; 16 lanes per rg broadcast the same address (free).
    __shared__ u32 h1u[64][64];
    __shared__ u32 h2u[64][64];
    int pbase = blockIdx.x * 64;
    int tid = threadIdx.x;
    const uint4* hfu4 = (const uint4*)hf;   // 16 uint4 per 128-bf16 row
    for (int id = tid; id < 64 * 16; id += 256) {
        int p = id >> 4;
        int c4 = (id & 15) << 2;
        int c4s = c4 ^ ((p & 3) << 2);
        int gp = pbase + p;
        uint4 v1 = make_uint4(0u, 0u, 0u, 0u), v2 = v1;
        if (gp < NPAIR) {
            v1 = hfu4[x1[gp] * 16 + (id & 15)];
            v2 = hfu4[x2[gp] * 16 + (id & 15)];
        }
        *(uint4*)&h1u[p][c4s] = v1;
        *(uint4*)&h2u[p][c4s] = v2;
    }
    __syncthreads();
    int cg = tid & 15;          // 16 col groups x 8 = 128 cols
    int c8 = cg << 3;
    int rg = tid >> 4;          // 16 row groups x 4 = 64 pairs
    float acc[4][8] = {};
    for (int kb = 0; kb < 32; ++kb) {       // k = 4*kb + kk
        uint2 u1[4], u2[4];
        #pragma unroll
        for (int i = 0; i < 4; ++i) {
            int row = rg + (i << 4);
            int ci = (kb << 1) ^ ((row & 3) << 2);
            u1[i] = *(uint2*)&h1u[row][ci];
            u2[i] = *(uint2*)&h2u[row][ci];
        }
        #pragma unroll
        for (int kk = 0; kk < 4; ++kk) {
            int k = (kb << 2) + kk;
            float a1v[4], a2v[4], adv[4];
            #pragma unroll
            for (int i = 0; i < 4; ++i) {
                u32 w1b = (kk < 2) ? u1[i].x : u1[i].y;
                u32 w2b = (kk < 2) ? u2[i].x : u2[i].y;
                a1v[i] = (kk & 1) ? bfhi(w1b) : bflo(w1b);
                a2v[i] = (kk & 1) ? bfhi(w2b) : bflo(w2b);
                adv[i] = fabsf(a1v[i] - a2v[i]);
            }
            float4 wA0 = *(const float4*)&w1[k * 128 + c8];
            float4 wA1 = *(const float4*)&w1[k * 128 + c8 + 4];
            float4 wB0 = *(const float4*)&w1[(128 + k) * 128 + c8];
            float4 wB1 = *(const float4*)&w1[(128 + k) * 128 + c8 + 4];
            float4 wC0 = *(const float4*)&w1[(256 + k) * 128 + c8];
            float4 wC1 = *(const float4*)&w1[(256 + k) * 128 + c8 + 4];
            #pragma unroll
            for (int i = 0; i < 4; ++i) {
                acc[i][0] += a1v[i] * wA0.x + a2v[i] * wB0.x + adv[i] * wC0.x;
                acc[i][1] += a1v[i] * wA0.y + a2v[i] * wB0.y + adv[i] * wC0.y;
                acc[i][2] += a1v[i] * wA0.z + a2v[i] * wB0.z + adv[i] * wC0.z;
                acc[i][3] += a1v[i] * wA0.w + a2v[i] * wB0.w + adv[i] * wC0.w;
                acc[i][4] += a1v[i] * wA1.x + a2v[i] * wB1.x + adv[i] * wC1.x;
                acc[i][5] += a1v[i] * wA1.y + a2v[i] * wB1.y + adv[i] * wC1.y;
                acc[i][6] += a1v[i] * wA1.z + a2v[i] * wB1.z + adv[i] * wC1.z;
                acc[i][7] += a1v[i] * wA1.w + a2v[i] * wB1.w + adv[i] * wC1.w;
            }
        }
    }
    float4 bv0 = *(const float4*)&b1[c8];
    float4 bv1 = *(const float4*)&b1[c8 + 4];
    float bb[8] = { bv0.x, bv0.y, bv0.z, bv0.w, bv1.x, bv1.y, bv1.z, bv1.w };
    float w20[8], w21[8];
    #pragma unroll
    for (int j = 0; j < 8; ++j) { w20[j] = w2[(c8 + j) * 2 + 0]; w21[j] = w2[(c8 + j) * 2 + 1]; }
    float ob0 = b2[0], ob1 = b2[1];
    #pragma unroll
    for (int i = 0; i < 4; ++i) {
        float p0 = 0.f, p1 = 0.f;
        #pragma unroll
        for (int j = 0; j < 8; ++j) {
            float z = fmaxf(acc[i][j] + bb[j], 0.f);
            p0 += z * w20[j]; p1 += z * w21[j];
        }
        #pragma unroll
        for (int m = 1; m < 16; m <<= 1) { p0 += __shfl_xor(p0, m); p1 += __shfl_xor(p1, m); }
        int gp = pbase + rg + 16 * i;
        if (cg == 0 && gp < NPAIR) {
            out[gp * 2 + 0] = p0 + ob0;
            out[gp * 2 + 1] = p1 + ob1;
        }
    }
}

extern "C" void kernel_launch(void* const* d_in, const int* in_sizes, int n_in,
                              void* d_out, int out_size, void* d_ws, size_t ws_size,
                              hipStream_t stream) {
    const int*   src = (const int*)d_in[0];
    const int*   dst = (const int*)d_in[1];
    const float* h   = (const float*)d_in[2];
    const int*   x1  = (const int*)d_in[3];
    const int*   x2  = (const int*)d_in[4];
    const float* W0  = (const float*)d_in[5];
    const float* al0 = (const float*)d_in[6];
    const float* ar0 = (const float*)d_in[7];
    const float* W1  = (const float*)d_in[8];
    const float* al1 = (const float*)d_in[9];
    const float* ar1 = (const float*)d_in[10];
    const float* w1  = (const float*)d_in[11];
    const float* b1  = (const float*)d_in[12];
    const float* w2  = (const float*)d_in[13];
    const float* b2  = (const float*)d_in[14];
    float* out = (float*)d_out;

    char* ws = (char*)d_ws;
    size_t o = 0;
    auto alloc = [&](size_t bytes) { size_t r = o; o = (o + bytes + 255) & ~255UL; return r; };
    int* off    = (int*)(ws + alloc((NN + 1) * sizeof(int)));
    int* cursor = (int*)(ws + alloc(NN * sizeof(int)));
    int* bsums  = (int*)(ws + alloc(256 * sizeof(int)));
    int* elist  = (int*)(ws + alloc(NE * sizeof(int)));
    float* att  = (float*)(ws + alloc((size_t)NN * 4 * sizeof(float)));
    u16* feat   = (u16*)(ws + alloc((size_t)NN * 256 * sizeof(u16)));
    u16* hb0    = (u16*)(ws + alloc((size_t)NN * 128 * sizeof(u16)));
    u16* hb1    = (u16*)(ws + alloc((size_t)NN * 128 * sizeof(u16)));

    hipMemsetAsync(off, 0, (NN + 1) * sizeof(int), stream);
    hipMemsetAsync(cursor, 0, NN * sizeof(int), stream);

    int eblocks = (NE + 255) / 256;
    int nscan = NN + 1;
    int nb = (nscan + 255) / 256;
    count_kernel<<<eblocks, 256, 0, stream>>>(dst, off);
    scan1<<<nb, 256, 0, stream>>>(off, bsums, nscan);
    scan2<<<1, 256, 0, stream>>>(bsums, nb);
    scan3<<<nb, 256, 0, stream>>>(off, bsums, nscan);
    fill_kernel<<<eblocks, 256, 0, stream>>>(dst, off, cursor, elist);

    dim3 ggrid((NN + 63) / 64, 2);
    // layer 0 (A fp32)
    gemm_fused<false><<<ggrid, 256, 0, stream>>>((const void*)h, W0, al0, ar0, feat, att, NN);
    aggregate<<<NN, 128, 0, stream>>>(feat, off, elist, src, att, hb0);
    // layer 1 (A bf16)
    gemm_fused<true><<<ggrid, 256, 0, stream>>>((const void*)hb0, W1, al1, ar1, feat, att, NN);
    aggregate<<<NN, 128, 0, stream>>>(feat, off, elist, src, att, hb1);
    // pair MLP
    mlp_kernel<<<(NPAIR + 63) / 64, 256, 0, stream>>>(hb1, x1, x2, w1, b1, w2, b2, out);
}

// Round 5
// 502.821 us; speedup vs baseline: 1.8622x; 1.3332x over previous
//
#include <hip/hip_runtime.h>
#include <hip/hip_bf16.h>

#define NN 50000
#define NE 800000
#define NPAIR 100000

typedef unsigned int u32;
typedef unsigned short u16;
typedef __attribute__((ext_vector_type(8))) short short8;
typedef __attribute__((ext_vector_type(4))) float f32x4;

__device__ __forceinline__ float bflo(u32 u) { return __uint_as_float(u << 16); }
__device__ __forceinline__ float bfhi(u32 u) { return __uint_as_float(u & 0xffff0000u); }
__device__ __forceinline__ u32 bfround(float f) {
    u32 u = __float_as_uint(f);
    return (u + 0x7fffu + ((u >> 16) & 1u)) >> 16;
}
__device__ __forceinline__ u32 packbf(float a, float b) {
    return bfround(a) | (bfround(b) << 16);
}

// ---------------- CSR build ----------------
__global__ __launch_bounds__(256) void count_kernel(const int* __restrict__ dst, int* __restrict__ off) {
    int e = blockIdx.x * 256 + threadIdx.x;
    if (e < NE) atomicAdd(&off[dst[e] + 1], 1);
}

__global__ __launch_bounds__(256) void scan1(int* __restrict__ data, int* __restrict__ bsums, int n) {
    int tid = threadIdx.x;
    int i = blockIdx.x * 256 + tid;
    int v = (i < n) ? data[i] : 0;
    #pragma unroll
    for (int d = 1; d < 64; d <<= 1) {
        int t = __shfl_up(v, d);
        if ((tid & 63) >= d) v += t;
    }
    __shared__ int ws[4];
    if ((tid & 63) == 63) ws[tid >> 6] = v;
    __syncthreads();
    int w = tid >> 6;
    if (w > 0) v += ws[0];
    if (w > 1) v += ws[1];
    if (w > 2) v += ws[2];
    if (i < n) data[i] = v;
    if (tid == 255) bsums[blockIdx.x] = v;
}

__global__ __launch_bounds__(256) void scan2(int* __restrict__ bsums, int nb) {
    int tid = threadIdx.x;
    int v = (tid < nb) ? bsums[tid] : 0;
    #pragma unroll
    for (int d = 1; d < 64; d <<= 1) {
        int t = __shfl_up(v, d);
        if ((tid & 63) >= d) v += t;
    }
    __shared__ int ws[4];
    if ((tid & 63) == 63) ws[tid >> 6] = v;
    __syncthreads();
    int w = tid >> 6;
    if (w > 0) v += ws[0];
    if (w > 1) v += ws[1];
    if (w > 2) v += ws[2];
    if (tid < nb) bsums[tid] = v;
}

__global__ __launch_bounds__(256) void scan3(int* __restrict__ data, const int* __restrict__ bsums, int n) {
    int i = blockIdx.x * 256 + threadIdx.x;
    if (i < n && blockIdx.x > 0) data[i] += bsums[blockIdx.x - 1];
}

__global__ __launch_bounds__(256) void fill_kernel(const int* __restrict__ dst, const int* __restrict__ off,
                                                   int* __restrict__ cursor, int* __restrict__ elist) {
    int e = blockIdx.x * 256 + threadIdx.x;
    if (e < NE) {
        int d = dst[e];
        int pos = off[d] + atomicAdd(&cursor[d], 1);
        elist[pos] = e;
    }
}

// ---- fused GEMM + attention-coef: C(bf16)[nrows,256] = A[nrows,128]@W[128,256] ----
template<bool ABF16>
__global__ __launch_bounds__(256) void gemm_fused(const void* __restrict__ Av,
                                                  const float* __restrict__ W,
                                                  const float* __restrict__ al,
                                                  const float* __restrict__ ar,
                                                  u16* __restrict__ C,
                                                  float* __restrict__ att, int nrows) {
    __shared__ float As[64][133];
    int rbase = blockIdx.x * 64;
    int head = blockIdx.y;
    int cbase = head * 128;
    int tid = threadIdx.x;
    if (ABF16) {
        const u16* A = (const u16*)Av;
        for (int id = tid; id < 64 * 16; id += 256) {
            int r = id >> 4, c8 = (id & 15) << 3;
            int gr = rbase + r;
            uint4 v = make_uint4(0u, 0u, 0u, 0u);
            if (gr < nrows) v = *(const uint4*)&A[gr * 128 + c8];
            As[r][c8 + 0] = bflo(v.x); As[r][c8 + 1] = bfhi(v.x);
            As[r][c8 + 2] = bflo(v.y); As[r][c8 + 3] = bfhi(v.y);
            As[r][c8 + 4] = bflo(v.z); As[r][c8 + 5] = bfhi(v.z);
            As[r][c8 + 6] = bflo(v.w); As[r][c8 + 7] = bfhi(v.w);
        }
    } else {
        const float* A = (const float*)Av;
        for (int t = tid; t < 64 * 32; t += 256) {
            int r = t >> 5, c4 = (t & 31) << 2;
            int gr = rbase + r;
            float4 v = make_float4(0.f, 0.f, 0.f, 0.f);
            if (gr < nrows) v = *(const float4*)&A[gr * 128 + c4];
            As[r][c4 + 0] = v.x; As[r][c4 + 1] = v.y; As[r][c4 + 2] = v.z; As[r][c4 + 3] = v.w;
        }
    }
    __syncthreads();
    int cg = tid & 15;
    int c8 = cg << 3;
    int rg = tid >> 4;
    float acc[4][8] = {};
    #pragma unroll 2
    for (int k = 0; k < 128; ++k) {
        float4 w0 = *(const float4*)&W[k * 256 + cbase + c8];
        float4 w1 = *(const float4*)&W[k * 256 + cbase + c8 + 4];
        float a[4];
        #pragma unroll
        for (int i = 0; i < 4; ++i) a[i] = As[rg + 16 * i][k];
        #pragma unroll
        for (int i = 0; i < 4; ++i) {
            acc[i][0] += a[i] * w0.x; acc[i][1] += a[i] * w0.y;
            acc[i][2] += a[i] * w0.z; acc[i][3] += a[i] * w0.w;
            acc[i][4] += a[i] * w1.x; acc[i][5] += a[i] * w1.y;
            acc[i][6] += a[i] * w1.z; acc[i][7] += a[i] * w1.w;
        }
    }
    float4 al0 = *(const float4*)&al[cbase + c8];
    float4 al1 = *(const float4*)&al[cbase + c8 + 4];
    float4 ar0 = *(const float4*)&ar[cbase + c8];
    float4 ar1 = *(const float4*)&ar[cbase + c8 + 4];
    u32* Cu = (u32*)C;
    #pragma unroll
    for (int i = 0; i < 4; ++i) {
        int gr = rbase + rg + 16 * i;
        float pl = acc[i][0] * al0.x + acc[i][1] * al0.y + acc[i][2] * al0.z + acc[i][3] * al0.w
                 + acc[i][4] * al1.x + acc[i][5] * al1.y + acc[i][6] * al1.z + acc[i][7] * al1.w;
        float pr = acc[i][0] * ar0.x + acc[i][1] * ar0.y + acc[i][2] * ar0.z + acc[i][3] * ar0.w
                 + acc[i][4] * ar1.x + acc[i][5] * ar1.y + acc[i][6] * ar1.z + acc[i][7] * ar1.w;
        #pragma unroll
        for (int m = 1; m < 16; m <<= 1) { pl += __shfl_xor(pl, m); pr += __shfl_xor(pr, m); }
        if (gr < nrows) {
            uint4 q;
            q.x = packbf(acc[i][0], acc[i][1]);
            q.y = packbf(acc[i][2], acc[i][3]);
            q.z = packbf(acc[i][4], acc[i][5]);
            q.w = packbf(acc[i][6], acc[i][7]);
            *(uint4*)&Cu[gr * 128 + ((cbase + c8) >> 1)] = q;
            if (cg == 0) {
                att[gr * 4 + head] = pl;
                att[gr * 4 + 2 + head] = pr;
            }
        }
    }
}

// ---------------- per-dst softmax + aggregation + relu + head-mean (bf16 feat) ----------------
__global__ __launch_bounds__(128) void aggregate(const u16* __restrict__ feat,
                                                 const int* __restrict__ off,
                                                 const int* __restrict__ elist,
                                                 const int* __restrict__ srcv,
                                                 const float* __restrict__ att,
                                                 u16* __restrict__ hout) {
    int v = blockIdx.x;
    int s = off[v], e_end = off[v + 1];
    int deg = e_end - s;
    int tid = threadIdx.x;
    u32* houtu = (u32*)hout;
    const u32* featu = (const u32*)feat;
    if (deg == 0) {
        if (tid < 64) houtu[v * 64 + tid] = 0u;
        return;
    }
    const float4* att4 = (const float4*)att;
    float4 av = att4[v];
    float er0 = av.z, er1 = av.w;
    int h = tid >> 6;
    int wave = h;

    __shared__ int ush[256];
    __shared__ float w0sh[256], w1sh[256];
    __shared__ float red[2][4];
    __shared__ float dsh[2];
    __shared__ float2 osh[128];

    float accx = 0.f, accy = 0.f;
    const float* wh = h ? w1sh : w0sh;

    if (deg <= 256) {
        float e0a[2], e1a[2];
        float m0 = -1e30f, m1 = -1e30f;
        #pragma unroll
        for (int jj = 0; jj < 2; ++jj) {
            int j = tid + 128 * jj;
            e0a[jj] = -1e30f; e1a[jj] = -1e30f;
            if (j < deg) {
                int u = srcv[elist[s + j]];
                ush[j] = u;
                float4 au = att4[u];
                float a0 = au.x + er0; a0 = a0 > 0.f ? a0 : 0.2f * a0;
                float a1 = au.y + er1; a1 = a1 > 0.f ? a1 : 0.2f * a1;
                e0a[jj] = a0; e1a[jj] = a1;
                m0 = fmaxf(m0, a0); m1 = fmaxf(m1, a1);
            }
        }
        #pragma unroll
        for (int m = 1; m < 64; m <<= 1) {
            m0 = fmaxf(m0, __shfl_xor(m0, m));
            m1 = fmaxf(m1, __shfl_xor(m1, m));
        }
        if ((tid & 63) == 0) { red[wave][0] = m0; red[wave][1] = m1; }
        __syncthreads();
        m0 = fmaxf(red[0][0], red[1][0]);
        m1 = fmaxf(red[0][1], red[1][1]);
        float s0 = 0.f, s1 = 0.f;
        #pragma unroll
        for (int jj = 0; jj < 2; ++jj) {
            int j = tid + 128 * jj;
            if (j < deg) {
                float w0 = __expf(e0a[jj] - m0), w1 = __expf(e1a[jj] - m1);
                w0sh[j] = w0; w1sh[j] = w1;
                s0 += w0; s1 += w1;
            }
        }
        #pragma unroll
        for (int m = 1; m < 64; m <<= 1) { s0 += __shfl_xor(s0, m); s1 += __shfl_xor(s1, m); }
        if ((tid & 63) == 0) { red[wave][2] = s0; red[wave][3] = s1; }
        __syncthreads();
        if (tid == 0) {
            dsh[0] = red[0][2] + red[1][2];
            dsh[1] = red[0][3] + red[1][3];
        }
        __syncthreads();
        int k = 0;
        for (; k + 4 <= deg; k += 4) {
            int u0 = ush[k], u1 = ush[k + 1], u2 = ush[k + 2], u3 = ush[k + 3];
            float q0 = wh[k], q1 = wh[k + 1], q2 = wh[k + 2], q3 = wh[k + 3];
            u32 f0 = featu[u0 * 128 + tid];
            u32 f1 = featu[u1 * 128 + tid];
            u32 f2 = featu[u2 * 128 + tid];
            u32 f3 = featu[u3 * 128 + tid];
            accx += q0 * bflo(f0) + q1 * bflo(f1) + q2 * bflo(f2) + q3 * bflo(f3);
            accy += q0 * bfhi(f0) + q1 * bfhi(f1) + q2 * bfhi(f2) + q3 * bfhi(f3);
        }
        for (; k < deg; ++k) {
            u32 fu = featu[ush[k] * 128 + tid];
            accx += wh[k] * bflo(fu);
            accy += wh[k] * bfhi(fu);
        }
    } else {
        float m0 = -1e30f, m1 = -1e30f;
        for (int idx = s + tid; idx < e_end; idx += 128) {
            int u = srcv[elist[idx]];
            float4 au = att4[u];
            float a0 = au.x + er0; a0 = a0 > 0.f ? a0 : 0.2f * a0;
            float a1 = au.y + er1; a1 = a1 > 0.f ? a1 : 0.2f * a1;
            m0 = fmaxf(m0, a0); m1 = fmaxf(m1, a1);
        }
        #pragma unroll
        for (int m = 1; m < 64; m <<= 1) {
            m0 = fmaxf(m0, __shfl_xor(m0, m));
            m1 = fmaxf(m1, __shfl_xor(m1, m));
        }
        if ((tid & 63) == 0) { red[wave][0] = m0; red[wave][1] = m1; }
        __syncthreads();
        m0 = fmaxf(red[0][0], red[1][0]);
        m1 = fmaxf(red[0][1], red[1][1]);
        float dsum0 = 0.f, dsum1 = 0.f;
        for (int cb = 0; cb < deg; cb += 128) {
            int cn = min(128, deg - cb);
            __syncthreads();
            if (tid < cn) {
                int u = srcv[elist[s + cb + tid]];
                float4 au = att4[u];
                float a0 = au.x + er0; a0 = a0 > 0.f ? a0 : 0.2f * a0;
                float a1 = au.y + er1; a1 = a1 > 0.f ? a1 : 0.2f * a1;
                float w0 = __expf(a0 - m0), w1 = __expf(a1 - m1);
                w0sh[tid] = w0; w1sh[tid] = w1; ush[tid] = u;
                dsum0 += w0; dsum1 += w1;
            }
            __syncthreads();
            for (int k = 0; k < cn; ++k) {
                u32 fu = featu[ush[k] * 128 + tid];
                accx += wh[k] * bflo(fu);
                accy += wh[k] * bfhi(fu);
            }
        }
        #pragma unroll
        for (int m = 1; m < 64; m <<= 1) { dsum0 += __shfl_xor(dsum0, m); dsum1 += __shfl_xor(dsum1, m); }
        __syncthreads();
        if ((tid & 63) == 0) { red[wave][2] = dsum0; red[wave][3] = dsum1; }
        __syncthreads();
        if (tid == 0) {
            dsh[0] = red[0][2] + red[1][2];
            dsh[1] = red[0][3] + red[1][3];
        }
        __syncthreads();
    }
    float d = dsh[h] + 1e-9f;
    float ox = fmaxf(accx / d, 0.f);
    float oy = fmaxf(accy / d, 0.f);
    osh[tid] = make_float2(ox, oy);
    __syncthreads();
    if (tid < 64) {
        float2 a = osh[tid], b = osh[tid + 64];
        houtu[v * 64 + tid] = packbf(0.5f * (a.x + b.x), 0.5f * (a.y + b.y));
    }
}

// ---- pack w1 (fp32 [384,128]) into bf16 MFMA B-fragment order ----
// frag layout (a): lane l holds B[k=(l>>4)*8+j][n=ct*16+(l&15)], j=0..7 contiguous.
// w1p[((kt*8+ct)*64 + lane)*8 + j]
__global__ __launch_bounds__(256) void pack_w1(const float* __restrict__ w1, u16* __restrict__ w1p) {
    int id = blockIdx.x * 256 + threadIdx.x;
    if (id < 384 * 128) {
        int k = id >> 7, n = id & 127;
        int kt = k >> 5, kk = k & 31, lg = kk >> 3, j = kk & 7;
        int ct = n >> 4, ln = n & 15;
        int lane = lg * 16 + ln;
        w1p[(((kt * 8 + ct) * 64) + lane) * 8 + j] = (u16)bfround(w1[id]);
    }
}

// ---------------- fused pair MLP via MFMA ----------------
// block = 256 thr (4 waves), 64 pairs. z[64][384+8] bf16 LDS.
// wave w: rows [w*16, w*16+16); 8 col-tiles x 12 K-steps of mfma_f32_16x16x32_bf16.
__global__ __launch_bounds__(256) void mlp_mfma(const u16* __restrict__ hf,
                                                const int* __restrict__ x1,
                                                const int* __restrict__ x2,
                                                const u16* __restrict__ w1p,
                                                const float* __restrict__ b1,
                                                const float* __restrict__ w2,
                                                const float* __restrict__ b2,
                                                float* __restrict__ out) {
    __shared__ u16 z[64][392];   // pad 392: row stride 784B -> banks 4r%32, 2-way max
    int pbase = blockIdx.x * 64;
    int tid = threadIdx.x;
    const uint4* hfu4 = (const uint4*)hf;   // 16 x uint4 per 128-bf16 row
    for (int id = tid; id < 64 * 16; id += 256) {
        int p = id >> 4, seg = id & 15;
        int gp = pbase + p;
        uint4 v1 = make_uint4(0u, 0u, 0u, 0u), v2 = v1;
        if (gp < NPAIR) {
            v1 = hfu4[x1[gp] * 16 + seg];
            v2 = hfu4[x2[gp] * 16 + seg];
        }
        int c8 = seg << 3;
        *(uint4*)&z[p][c8] = v1;
        *(uint4*)&z[p][128 + c8] = v2;
        uint4 vd;
        vd.x = packbf(fabsf(bflo(v1.x) - bflo(v2.x)), fabsf(bfhi(v1.x) - bfhi(v2.x)));
        vd.y = packbf(fabsf(bflo(v1.y) - bflo(v2.y)), fabsf(bfhi(v1.y) - bfhi(v2.y)));
        vd.z = packbf(fabsf(bflo(v1.z) - bflo(v2.z)), fabsf(bfhi(v1.z) - bfhi(v2.z)));
        vd.w = packbf(fabsf(bflo(v1.w) - bflo(v2.w)), fabsf(bfhi(v1.w) - bfhi(v2.w)));
        *(uint4*)&z[p][256 + c8] = vd;
    }
    __syncthreads();
    int l = tid & 63, w = tid >> 6;
    int lg = l >> 4, ln = l & 15;
    f32x4 acc[8];
    #pragma unroll
    for (int ct = 0; ct < 8; ++ct) acc[ct] = (f32x4){0.f, 0.f, 0.f, 0.f};
    const short8* wp = (const short8*)w1p;
    const u16* zr = &z[w * 16 + ln][lg * 8];
    for (int kt = 0; kt < 12; ++kt) {
        short8 a = *(const short8*)&zr[kt * 32];
        #pragma unroll
        for (int ct = 0; ct < 8; ++ct) {
            short8 b = wp[(kt * 8 + ct) * 64 + l];
            acc[ct] = __builtin_amdgcn_mfma_f32_16x16x32_bf16(a, b, acc[ct], 0, 0, 0);
        }
    }
    // epilogue: bias + relu + [128,2] layer + bias, reduce over 16 lanes (ln)
    float b1v[8], w20[8], w21[8];
    #pragma unroll
    for (int ct = 0; ct < 8; ++ct) {
        int n = ct * 16 + ln;
        b1v[ct] = b1[n];
        w20[ct] = w2[n * 2 + 0];
        w21[ct] = w2[n * 2 + 1];
    }
    float ob0 = b2[0], ob1 = b2[1];
    #pragma unroll
    for (int r = 0; r < 4; ++r) {
        float p0 = 0.f, p1 = 0.f;
        #pragma unroll
        for (int ct = 0; ct < 8; ++ct) {
            float zv = fmaxf(acc[ct][r] + b1v[ct], 0.f);
            p0 += zv * w20[ct]; p1 += zv * w21[ct];
        }
        #pragma unroll
        for (int m = 1; m < 16; m <<= 1) { p0 += __shfl_xor(p0, m); p1 += __shfl_xor(p1, m); }
        int gp = pbase + w * 16 + lg * 4 + r;
        if (ln == 0 && gp < NPAIR) {
            out[gp * 2 + 0] = p0 + ob0;
            out[gp * 2 + 1] = p1 + ob1;
        }
    }
}

extern "C" void kernel_launch(void* const* d_in, const int* in_sizes, int n_in,
                              void* d_out, int out_size, void* d_ws, size_t ws_size,
                              hipStream_t stream) {
    const int*   src = (const int*)d_in[0];
    const int*   dst = (const int*)d_in[1];
    const float* h   = (const float*)d_in[2];
    const int*   x1  = (const int*)d_in[3];
    const int*   x2  = (const int*)d_in[4];
    const float* W0  = (const float*)d_in[5];
    const float* al0 = (const float*)d_in[6];
    const float* ar0 = (const float*)d_in[7];
    const float* W1  = (const float*)d_in[8];
    const float* al1 = (const float*)d_in[9];
    const float* ar1 = (const float*)d_in[10];
    const float* w1  = (const float*)d_in[11];
    const float* b1  = (const float*)d_in[12];
    const float* w2  = (const float*)d_in[13];
    const float* b2  = (const float*)d_in[14];
    float* out = (float*)d_out;

    char* ws = (char*)d_ws;
    size_t o = 0;
    auto alloc = [&](size_t bytes) { size_t r = o; o = (o + bytes + 255) & ~255UL; return r; };
    int* off    = (int*)(ws + alloc((NN + 1) * sizeof(int)));
    int* cursor = (int*)(ws + alloc(NN * sizeof(int)));
    int* bsums  = (int*)(ws + alloc(256 * sizeof(int)));
    int* elist  = (int*)(ws + alloc(NE * sizeof(int)));
    float* att  = (float*)(ws + alloc((size_t)NN * 4 * sizeof(float)));
    u16* feat   = (u16*)(ws + alloc((size_t)NN * 256 * sizeof(u16)));
    u16* hb0    = (u16*)(ws + alloc((size_t)NN * 128 * sizeof(u16)));
    u16* hb1    = (u16*)(ws + alloc((size_t)NN * 128 * sizeof(u16)));
    u16* w1p    = (u16*)(ws + alloc((size_t)384 * 128 * sizeof(u16)));

    hipMemsetAsync(off, 0, (NN + 1) * sizeof(int), stream);
    hipMemsetAsync(cursor, 0, NN * sizeof(int), stream);

    int eblocks = (NE + 255) / 256;
    int nscan = NN + 1;
    int nb = (nscan + 255) / 256;
    count_kernel<<<eblocks, 256, 0, stream>>>(dst, off);
    scan1<<<nb, 256, 0, stream>>>(off, bsums, nscan);
    scan2<<<1, 256, 0, stream>>>(bsums, nb);
    scan3<<<nb, 256, 0, stream>>>(off, bsums, nscan);
    fill_kernel<<<eblocks, 256, 0, stream>>>(dst, off, cursor, elist);
    pack_w1<<<192, 256, 0, stream>>>(w1, w1p);

    dim3 ggrid((NN + 63) / 64, 2);
    // layer 0 (A fp32)
    gemm_fused<false><<<ggrid, 256, 0, stream>>>((const void*)h, W0, al0, ar0, feat, att, NN);
    aggregate<<<NN, 128, 0, stream>>>(feat, off, elist, src, att, hb0);
    // layer 1 (A bf16)
    gemm_fused<true><<<ggrid, 256, 0, stream>>>((const void*)hb0, W1, al1, ar1, feat, att, NN);
    aggregate<<<NN, 128, 0, stream>>>(feat, off, elist, src, att, hb1);
    // pair MLP (MFMA)
    mlp_mfma<<<(NPAIR + 63) / 64, 256, 0, stream>>>(hb1, x1, x2, w1p, b1, w2, b2, out);
}

// Round 7
// 406.797 us; speedup vs baseline: 2.3017x; 1.2360x over previous
//
#include <hip/hip_runtime.h>
#include <hip/hip_bf16.h>

#define NN 50000
#define NE 800000
#define NPAIR 100000

typedef unsigned int u32;
typedef unsigned short u16;
typedef __attribute__((ext_vector_type(8))) short short8;
typedef __attribute__((ext_vector_type(4))) float f32x4;

__device__ __forceinline__ float bflo(u32 u) { return __uint_as_float(u << 16); }
__device__ __forceinline__ float bfhi(u32 u) { return __uint_as_float(u & 0xffff0000u); }
__device__ __forceinline__ u32 bfround(float f) {
    u32 u = __float_as_uint(f);
    return (u + 0x7fffu + ((u >> 16) & 1u)) >> 16;
}
__device__ __forceinline__ u32 packbf(float a, float b) {
    return bfround(a) | (bfround(b) << 16);
}

// ---------------- CSR build ----------------
__global__ __launch_bounds__(256) void count_kernel(const int* __restrict__ dst, int* __restrict__ off) {
    int e = blockIdx.x * 256 + threadIdx.x;
    if (e < NE) atomicAdd(&off[dst[e] + 1], 1);
}

__global__ __launch_bounds__(256) void scan1(int* __restrict__ data, int* __restrict__ bsums, int n) {
    int tid = threadIdx.x;
    int i = blockIdx.x * 256 + tid;
    int v = (i < n) ? data[i] : 0;
    #pragma unroll
    for (int d = 1; d < 64; d <<= 1) {
        int t = __shfl_up(v, d);
        if ((tid & 63) >= d) v += t;
    }
    __shared__ int ws[4];
    if ((tid & 63) == 63) ws[tid >> 6] = v;
    __syncthreads();
    int w = tid >> 6;
    if (w > 0) v += ws[0];
    if (w > 1) v += ws[1];
    if (w > 2) v += ws[2];
    if (i < n) data[i] = v;
    if (tid == 255) bsums[blockIdx.x] = v;
}

__global__ __launch_bounds__(256) void scan2(int* __restrict__ bsums, int nb) {
    int tid = threadIdx.x;
    int v = (tid < nb) ? bsums[tid] : 0;
    #pragma unroll
    for (int d = 1; d < 64; d <<= 1) {
        int t = __shfl_up(v, d);
        if ((tid & 63) >= d) v += t;
    }
    __shared__ int ws[4];
    if ((tid & 63) == 63) ws[tid >> 6] = v;
    __syncthreads();
    int w = tid >> 6;
    if (w > 0) v += ws[0];
    if (w > 1) v += ws[1];
    if (w > 2) v += ws[2];
    if (tid < nb) bsums[tid] = v;
}

__global__ __launch_bounds__(256) void scan3(int* __restrict__ data, const int* __restrict__ bsums, int n) {
    int i = blockIdx.x * 256 + threadIdx.x;
    if (i < n && blockIdx.x > 0) data[i] += bsums[blockIdx.x - 1];
}

// stores SRC NODE VALUE (not edge id) -> aggregate skips one indirection
__global__ __launch_bounds__(256) void fill_kernel(const int* __restrict__ src, const int* __restrict__ dst,
                                                   const int* __restrict__ off,
                                                   int* __restrict__ cursor, int* __restrict__ srcs) {
    int e = blockIdx.x * 256 + threadIdx.x;
    if (e < NE) {
        int d = dst[e];
        int pos = off[d] + atomicAdd(&cursor[d], 1);
        srcs[pos] = src[e];
    }
}

// ---- pack W (fp32 [128,256]) into bf16 MFMA B-fragment order ----
// lane l holds B[k=kt*32+(l>>4)*8+j][n=nt*16+(l&15)], j contiguous.
__global__ __launch_bounds__(256) void pack_wg(const float* __restrict__ W, u16* __restrict__ Wp) {
    int id = blockIdx.x * 256 + threadIdx.x;
    if (id < 128 * 256) {
        int k = id >> 8, n = id & 255;
        int kt = k >> 5, kk = k & 31, lg = kk >> 3, j = kk & 7;
        int nt = n >> 4, ln = n & 15;
        int lane = lg * 16 + ln;
        Wp[(((kt * 16 + nt) * 64) + lane) * 8 + j] = (u16)bfround(W[id]);
    }
}

// ---- MFMA GEMM + attention-coef: C(bf16)[nrows,256] = A[nrows,128]@W ; el/er ----
// 1 block = 64 rows x 256 cols (BOTH heads). 4 waves x 16 rows. bf16 MFMA, fp32 acc.
template<bool ABF16>
__global__ __launch_bounds__(256) void gemm_mfma(const void* __restrict__ Av,
                                                 const u16* __restrict__ Wp,
                                                 const float* __restrict__ al,
                                                 const float* __restrict__ ar,
                                                 u16* __restrict__ C,
                                                 float* __restrict__ att, int nrows) {
    // sbuf: phase 1 = As[64][136] bf16 (pad 136 -> 2-way max on frag reads);
    //       phase 2 = Cs[64][264] bf16 (transpose for coalesced store)
    __shared__ u16 sbuf[64 * 264];
    int rbase = blockIdx.x * 64;
    int tid = threadIdx.x;
    if (ABF16) {
        const uint4* A4 = (const uint4*)Av;   // 16 uint4 per 128-bf16 row
        for (int id = tid; id < 64 * 16; id += 256) {
            int r = id >> 4, seg = id & 15;
            int gr = rbase + r;
            uint4 v = make_uint4(0u, 0u, 0u, 0u);
            if (gr < nrows) v = A4[gr * 16 + seg];
            *(uint4*)&sbuf[r * 136 + seg * 8] = v;
        }
    } else {
        const float4* A4 = (const float4*)Av; // 32 float4 per 128-f32 row
        for (int id = tid; id < 64 * 32; id += 256) {
            int r = id >> 5, seg = id & 31;
            int gr = rbase + r;
            float4 v = make_float4(0.f, 0.f, 0.f, 0.f);
            if (gr < nrows) v = A4[gr * 32 + seg];
            uint2 p;
            p.x = packbf(v.x, v.y);
            p.y = packbf(v.z, v.w);
            *(uint2*)&sbuf[r * 136 + seg * 4] = p;
        }
    }
    __syncthreads();
    int l = tid & 63, w = tid >> 6;
    int ln = l & 15, lg = l >> 4;
    f32x4 acc[16];
    #pragma unroll
    for (int nt = 0; nt < 16; ++nt) acc[nt] = (f32x4){0.f, 0.f, 0.f, 0.f};
    const short8* wp = (const short8*)Wp;
    const u16* arow = &sbuf[(w * 16 + ln) * 136 + lg * 8];
    #pragma unroll
    for (int kt = 0; kt < 4; ++kt) {
        short8 a = *(const short8*)&arow[kt * 32];
        #pragma unroll
        for (int nt = 0; nt < 16; ++nt) {
            short8 b = wp[(kt * 16 + nt) * 64 + l];
            acc[nt] = __builtin_amdgcn_mfma_f32_16x16x32_bf16(a, b, acc[nt], 0, 0, 0);
        }
    }
    // epilogue 1: attention coefficients from fp32 accumulators
    float alv[16], arv[16];
    #pragma unroll
    for (int nt = 0; nt < 16; ++nt) {
        alv[nt] = al[nt * 16 + ln];
        arv[nt] = ar[nt * 16 + ln];
    }
    #pragma unroll
    for (int r = 0; r < 4; ++r) {
        float pl0 = 0.f, pr0 = 0.f, pl1 = 0.f, pr1 = 0.f;
        #pragma unroll
        for (int nt = 0; nt < 8; ++nt) {
            pl0 += acc[nt][r] * alv[nt];
            pr0 += acc[nt][r] * arv[nt];
            pl1 += acc[nt + 8][r] * alv[nt + 8];
            pr1 += acc[nt + 8][r] * arv[nt + 8];
        }
        #pragma unroll
        for (int m = 1; m < 16; m <<= 1) {
            pl0 += __shfl_xor(pl0, m); pr0 += __shfl_xor(pr0, m);
            pl1 += __shfl_xor(pl1, m); pr1 += __shfl_xor(pr1, m);
        }
        int grow = rbase + w * 16 + lg * 4 + r;
        if (ln == 0 && grow < nrows) {
            att[grow * 4 + 0] = pl0;   // el head0
            att[grow * 4 + 1] = pl1;   // el head1
            att[grow * 4 + 2] = pr0;   // er head0
            att[grow * 4 + 3] = pr1;   // er head1
        }
    }
    __syncthreads();   // done reading As; reuse sbuf as Cs
    // epilogue 2: transpose through LDS, coalesced bf16 store
    #pragma unroll
    for (int nt = 0; nt < 16; ++nt) {
        int col = nt * 16 + ln;
        #pragma unroll
        for (int r = 0; r < 4; ++r) {
            int row = w * 16 + lg * 4 + r;
            sbuf[row * 264 + col] = (u16)bfround(acc[nt][r]);
        }
    }
    __syncthreads();
    uint4* C4 = (uint4*)C;
    for (int id = tid; id < 64 * 32; id += 256) {
        int r = id >> 5, seg = id & 31;
        int gr = rbase + r;
        if (gr < nrows) C4[gr * 32 + seg] = *(uint4*)&sbuf[r * 264 + seg * 8];
    }
}

// ---------------- per-dst softmax + aggregation + relu + head-mean (bf16 feat) ----------------
__global__ __launch_bounds__(128) void aggregate(const u16* __restrict__ feat,
                                                 const int* __restrict__ off,
                                                 const int* __restrict__ srcs,
                                                 const float* __restrict__ att,
                                                 u16* __restrict__ hout) {
    int v = blockIdx.x;
    int s = off[v], e_end = off[v + 1];
    int deg = e_end - s;
    int tid = threadIdx.x;
    u32* houtu = (u32*)hout;
    const u32* featu = (const u32*)feat;
    if (deg == 0) {
        if (tid < 64) houtu[v * 64 + tid] = 0u;
        return;
    }
    const float4* att4 = (const float4*)att;
    float4 av = att4[v];
    float er0 = av.z, er1 = av.w;
    int h = tid >> 6;
    int wave = h;

    __shared__ int ush[256];
    __shared__ float w0sh[256], w1sh[256];
    __shared__ float red[2][4];
    __shared__ float dsh[2];
    __shared__ float2 osh[128];

    float accx = 0.f, accy = 0.f;
    const float* wh = h ? w1sh : w0sh;

    if (deg <= 256) {
        float e0a[2], e1a[2];
        float m0 = -1e30f, m1 = -1e30f;
        #pragma unroll
        for (int jj = 0; jj < 2; ++jj) {
            int j = tid + 128 * jj;
            e0a[jj] = -1e30f; e1a[jj] = -1e30f;
            if (j < deg) {
                int u = srcs[s + j];
                ush[j] = u;
                float4 au = att4[u];
                float a0 = au.x + er0; a0 = a0 > 0.f ? a0 : 0.2f * a0;
                float a1 = au.y + er1; a1 = a1 > 0.f ? a1 : 0.2f * a1;
                e0a[jj] = a0; e1a[jj] = a1;
                m0 = fmaxf(m0, a0); m1 = fmaxf(m1, a1);
            }
        }
        #pragma unroll
        for (int m = 1; m < 64; m <<= 1) {
            m0 = fmaxf(m0, __shfl_xor(m0, m));
            m1 = fmaxf(m1, __shfl_xor(m1, m));
        }
        if ((tid & 63) == 0) { red[wave][0] = m0; red[wave][1] = m1; }
        __syncthreads();
        m0 = fmaxf(red[0][0], red[1][0]);
        m1 = fmaxf(red[0][1], red[1][1]);
        float s0 = 0.f, s1 = 0.f;
        #pragma unroll
        for (int jj = 0; jj < 2; ++jj) {
            int j = tid + 128 * jj;
            if (j < deg) {
                float w0 = __expf(e0a[jj] - m0), w1 = __expf(e1a[jj] - m1);
                w0sh[j] = w0; w1sh[j] = w1;
                s0 += w0; s1 += w1;
            }
        }
        #pragma unroll
        for (int m = 1; m < 64; m <<= 1) { s0 += __shfl_xor(s0, m); s1 += __shfl_xor(s1, m); }
        if ((tid & 63) == 0) { red[wave][2] = s0; red[wave][3] = s1; }
        __syncthreads();
        if (tid == 0) {
            dsh[0] = red[0][2] + red[1][2];
            dsh[1] = red[0][3] + red[1][3];
        }
        __syncthreads();
        int k = 0;
        for (; k + 4 <= deg; k += 4) {
            int u0 = ush[k], u1 = ush[k + 1], u2 = ush[k + 2], u3 = ush[k + 3];
            float q0 = wh[k], q1 = wh[k + 1], q2 = wh[k + 2], q3 = wh[k + 3];
            u32 f0 = featu[u0 * 128 + tid];
            u32 f1 = featu[u1 * 128 + tid];
            u32 f2 = featu[u2 * 128 + tid];
            u32 f3 = featu[u3 * 128 + tid];
            accx += q0 * bflo(f0) + q1 * bflo(f1) + q2 * bflo(f2) + q3 * bflo(f3);
            accy += q0 * bfhi(f0) + q1 * bfhi(f1) + q2 * bfhi(f2) + q3 * bfhi(f3);
        }
        for (; k < deg; ++k) {
            u32 fu = featu[ush[k] * 128 + tid];
            accx += wh[k] * bflo(fu);
            accy += wh[k] * bfhi(fu);
        }
    } else {
        float m0 = -1e30f, m1 = -1e30f;
        for (int idx = s + tid; idx < e_end; idx += 128) {
            int u = srcs[idx];
            float4 au = att4[u];
            float a0 = au.x + er0; a0 = a0 > 0.f ? a0 : 0.2f * a0;
            float a1 = au.y + er1; a1 = a1 > 0.f ? a1 : 0.2f * a1;
            m0 = fmaxf(m0, a0); m1 = fmaxf(m1, a1);
        }
        #pragma unroll
        for (int m = 1; m < 64; m <<= 1) {
            m0 = fmaxf(m0, __shfl_xor(m0, m));
            m1 = fmaxf(m1, __shfl_xor(m1, m));
        }
        if ((tid & 63) == 0) { red[wave][0] = m0; red[wave][1] = m1; }
        __syncthreads();
        m0 = fmaxf(red[0][0], red[1][0]);
        m1 = fmaxf(red[0][1], red[1][1]);
        float dsum0 = 0.f, dsum1 = 0.f;
        for (int cb = 0; cb < deg; cb += 128) {
            int cn = min(128, deg - cb);
            __syncthreads();
            if (tid < cn) {
                int u = srcs[s + cb + tid];
                float4 au = att4[u];
                float a0 = au.x + er0; a0 = a0 > 0.f ? a0 : 0.2f * a0;
                float a1 = au.y + er1; a1 = a1 > 0.f ? a1 : 0.2f * a1;
                float w0 = __expf(a0 - m0), w1 = __expf(a1 - m1);
                w0sh[tid] = w0; w1sh[tid] = w1; ush[tid] = u;
                dsum0 += w0; dsum1 += w1;
            }
            __syncthreads();
            for (int k = 0; k < cn; ++k) {
                u32 fu = featu[ush[k] * 128 + tid];
                accx += wh[k] * bflo(fu);
                accy += wh[k] * bfhi(fu);
            }
        }
        #pragma unroll
        for (int m = 1; m < 64; m <<= 1) { dsum0 += __shfl_xor(dsum0, m); dsum1 += __shfl_xor(dsum1, m); }
        __syncthreads();
        if ((tid & 63) == 0) { red[wave][2] = dsum0; red[wave][3] = dsum1; }
        __syncthreads();
        if (tid == 0) {
            dsh[0] = red[0][2] + red[1][2];
            dsh[1] = red[0][3] + red[1][3];
        }
        __syncthreads();
    }
    float d = dsh[h] + 1e-9f;
    float ox = fmaxf(accx / d, 0.f);
    float oy = fmaxf(accy / d, 0.f);
    osh[tid] = make_float2(ox, oy);
    __syncthreads();
    if (tid < 64) {
        float2 a = osh[tid], b = osh[tid + 64];
        houtu[v * 64 + tid] = packbf(0.5f * (a.x + b.x), 0.5f * (a.y + b.y));
    }
}

// ---- pack w1 (fp32 [384,128]) into bf16 MFMA B-fragment order ----
__global__ __launch_bounds__(256) void pack_w1(const float* __restrict__ w1, u16* __restrict__ w1p) {
    int id = blockIdx.x * 256 + threadIdx.x;
    if (id < 384 * 128) {
        int k = id >> 7, n = id & 127;
        int kt = k >> 5, kk = k & 31, lg = kk >> 3, j = kk & 7;
        int ct = n >> 4, ln = n & 15;
        int lane = lg * 16 + ln;
        w1p[(((kt * 8 + ct) * 64) + lane) * 8 + j] = (u16)bfround(w1[id]);
    }
}

// ---------------- fused pair MLP via MFMA ----------------
__global__ __launch_bounds__(256) void mlp_mfma(const u16* __restrict__ hf,
                                                const int* __restrict__ x1,
                                                const int* __restrict__ x2,
                                                const u16* __restrict__ w1p,
                                                const float* __restrict__ b1,
                                                const float* __restrict__ w2,
                                                const float* __restrict__ b2,
                                                float* __restrict__ out) {
    __shared__ u16 z[64][392];
    int pbase = blockIdx.x * 64;
    int tid = threadIdx.x;
    const uint4* hfu4 = (const uint4*)hf;
    for (int id = tid; id < 64 * 16; id += 256) {
        int p = id >> 4, seg = id & 15;
        int gp = pbase + p;
        uint4 v1 = make_uint4(0u, 0u, 0u, 0u), v2 = v1;
        if (gp < NPAIR) {
            v1 = hfu4[x1[gp] * 16 + seg];
            v2 = hfu4[x2[gp] * 16 + seg];
        }
        int c8 = seg << 3;
        *(uint4*)&z[p][c8] = v1;
        *(uint4*)&z[p][128 + c8] = v2;
        uint4 vd;
        vd.x = packbf(fabsf(bflo(v1.x) - bflo(v2.x)), fabsf(bfhi(v1.x) - bfhi(v2.x)));
        vd.y = packbf(fabsf(bflo(v1.y) - bflo(v2.y)), fabsf(bfhi(v1.y) - bfhi(v2.y)));
        vd.z = packbf(fabsf(bflo(v1.z) - bflo(v2.z)), fabsf(bfhi(v1.z) - bfhi(v2.z)));
        vd.w = packbf(fabsf(bflo(v1.w) - bflo(v2.w)), fabsf(bfhi(v1.w) - bfhi(v2.w)));
        *(uint4*)&z[p][256 + c8] = vd;
    }
    __syncthreads();
    int l = tid & 63, w = tid >> 6;
    int lg = l >> 4, ln = l & 15;
    f32x4 acc[8];
    #pragma unroll
    for (int ct = 0; ct < 8; ++ct) acc[ct] = (f32x4){0.f, 0.f, 0.f, 0.f};
    const short8* wp = (const short8*)w1p;
    const u16* zr = &z[w * 16 + ln][lg * 8];
    for (int kt = 0; kt < 12; ++kt) {
        short8 a = *(const short8*)&zr[kt * 32];
        #pragma unroll
        for (int ct = 0; ct < 8; ++ct) {
            short8 b = wp[(kt * 8 + ct) * 64 + l];
            acc[ct] = __builtin_amdgcn_mfma_f32_16x16x32_bf16(a, b, acc[ct], 0, 0, 0);
        }
    }
    float b1v[8], w20[8], w21[8];
    #pragma unroll
    for (int ct = 0; ct < 8; ++ct) {
        int n = ct * 16 + ln;
        b1v[ct] = b1[n];
        w20[ct] = w2[n * 2 + 0];
        w21[ct] = w2[n * 2 + 1];
    }
    float ob0 = b2[0], ob1 = b2[1];
    #pragma unroll
    for (int r = 0; r < 4; ++r) {
        float p0 = 0.f, p1 = 0.f;
        #pragma unroll
        for (int ct = 0; ct < 8; ++ct) {
            float zv = fmaxf(acc[ct][r] + b1v[ct], 0.f);
            p0 += zv * w20[ct]; p1 += zv * w21[ct];
        }
        #pragma unroll
        for (int m = 1; m < 16; m <<= 1) { p0 += __shfl_xor(p0, m); p1 += __shfl_xor(p1, m); }
        int gp = pbase + w * 16 + lg * 4 + r;
        if (ln == 0 && gp < NPAIR) {
            out[gp * 2 + 0] = p0 + ob0;
            out[gp * 2 + 1] = p1 + ob1;
        }
    }
}

extern "C" void kernel_launch(void* const* d_in, const int* in_sizes, int n_in,
                              void* d_out, int out_size, void* d_ws, size_t ws_size,
                              hipStream_t stream) {
    const int*   src = (const int*)d_in[0];
    const int*   dst = (const int*)d_in[1];
    const float* h   = (const float*)d_in[2];
    const int*   x1  = (const int*)d_in[3];
    const int*   x2  = (const int*)d_in[4];
    const float* W0  = (const float*)d_in[5];
    const float* al0 = (const float*)d_in[6];
    const float* ar0 = (const float*)d_in[7];
    const float* W1  = (const float*)d_in[8];
    const float* al1 = (const float*)d_in[9];
    const float* ar1 = (const float*)d_in[10];
    const float* w1  = (const float*)d_in[11];
    const float* b1  = (const float*)d_in[12];
    const float* w2  = (const float*)d_in[13];
    const float* b2  = (const float*)d_in[14];
    float* out = (float*)d_out;

    char* ws = (char*)d_ws;
    size_t o = 0;
    auto alloc = [&](size_t bytes) { size_t r = o; o = (o + bytes + 255) & ~255UL; return r; };
    int* off    = (int*)(ws + alloc((NN + 1) * sizeof(int)));
    int* cursor = (int*)(ws + alloc(NN * sizeof(int)));
    int* bsums  = (int*)(ws + alloc(256 * sizeof(int)));
    int* srcs   = (int*)(ws + alloc(NE * sizeof(int)));
    float* att  = (float*)(ws + alloc((size_t)NN * 4 * sizeof(float)));
    u16* feat   = (u16*)(ws + alloc((size_t)NN * 256 * sizeof(u16)));
    u16* hb0    = (u16*)(ws + alloc((size_t)NN * 128 * sizeof(u16)));
    u16* hb1    = (u16*)(ws + alloc((size_t)NN * 128 * sizeof(u16)));
    u16* w1p    = (u16*)(ws + alloc((size_t)384 * 128 * sizeof(u16)));
    u16* w0pg   = (u16*)(ws + alloc((size_t)128 * 256 * sizeof(u16)));
    u16* w1pg   = (u16*)(ws + alloc((size_t)128 * 256 * sizeof(u16)));

    hipMemsetAsync(off, 0, (NN + 1) * sizeof(int), stream);
    hipMemsetAsync(cursor, 0, NN * sizeof(int), stream);

    int eblocks = (NE + 255) / 256;
    int nscan = NN + 1;
    int nb = (nscan + 255) / 256;
    count_kernel<<<eblocks, 256, 0, stream>>>(dst, off);
    scan1<<<nb, 256, 0, stream>>>(off, bsums, nscan);
    scan2<<<1, 256, 0, stream>>>(bsums, nb);
    scan3<<<nb, 256, 0, stream>>>(off, bsums, nscan);
    fill_kernel<<<eblocks, 256, 0, stream>>>(src, dst, off, cursor, srcs);
    pack_wg<<<128, 256, 0, stream>>>(W0, w0pg);
    pack_wg<<<128, 256, 0, stream>>>(W1, w1pg);
    pack_w1<<<192, 256, 0, stream>>>(w1, w1p);

    int gblocks = (NN + 63) / 64;
    // layer 0 (A fp32)
    gemm_mfma<false><<<gblocks, 256, 0, stream>>>((const void*)h, w0pg, al0, ar0, feat, att, NN);
    aggregate<<<NN, 128, 0, stream>>>(feat, off, srcs, att, hb0);
    // layer 1 (A bf16)
    gemm_mfma<true><<<gblocks, 256, 0, stream>>>((const void*)hb0, w1pg, al1, ar1, feat, att, NN);
    aggregate<<<NN, 128, 0, stream>>>(feat, off, srcs, att, hb1);
    // pair MLP (MFMA)
    mlp_mfma<<<(NPAIR + 63) / 64, 256, 0, stream>>>(hb1, x1, x2, w1p, b1, w2, b2, out);
}

// Round 8
// 383.240 us; speedup vs baseline: 2.4432x; 1.0615x over previous
//
#include <hip/hip_runtime.h>
#include <hip/hip_bf16.h>

#define NN 50000
#define NE 800000
#define NPAIR 100000

typedef unsigned int u32;
typedef unsigned short u16;
typedef __attribute__((ext_vector_type(8))) short short8;
typedef __attribute__((ext_vector_type(4))) float f32x4;

__device__ __forceinline__ float bflo(u32 u) { return __uint_as_float(u << 16); }
__device__ __forceinline__ float bfhi(u32 u) { return __uint_as_float(u & 0xffff0000u); }
__device__ __forceinline__ u32 bfround(float f) {
    u32 u = __float_as_uint(f);
    return (u + 0x7fffu + ((u >> 16) & 1u)) >> 16;
}
__device__ __forceinline__ u32 packbf(float a, float b) {
    return bfround(a) | (bfround(b) << 16);
}

// ---------------- CSR build ----------------
__global__ __launch_bounds__(256) void count_kernel(const int* __restrict__ dst, int* __restrict__ off) {
    int e = blockIdx.x * 256 + threadIdx.x;
    if (e < NE) atomicAdd(&off[dst[e] + 1], 1);
}

__global__ __launch_bounds__(256) void scan1(int* __restrict__ data, int* __restrict__ bsums, int n) {
    int tid = threadIdx.x;
    int i = blockIdx.x * 256 + tid;
    int v = (i < n) ? data[i] : 0;
    #pragma unroll
    for (int d = 1; d < 64; d <<= 1) {
        int t = __shfl_up(v, d);
        if ((tid & 63) >= d) v += t;
    }
    __shared__ int ws[4];
    if ((tid & 63) == 63) ws[tid >> 6] = v;
    __syncthreads();
    int w = tid >> 6;
    if (w > 0) v += ws[0];
    if (w > 1) v += ws[1];
    if (w > 2) v += ws[2];
    if (i < n) data[i] = v;
    if (tid == 255) bsums[blockIdx.x] = v;
}

__global__ __launch_bounds__(256) void scan2(int* __restrict__ bsums, int nb) {
    int tid = threadIdx.x;
    int v = (tid < nb) ? bsums[tid] : 0;
    #pragma unroll
    for (int d = 1; d < 64; d <<= 1) {
        int t = __shfl_up(v, d);
        if ((tid & 63) >= d) v += t;
    }
    __shared__ int ws[4];
    if ((tid & 63) == 63) ws[tid >> 6] = v;
    __syncthreads();
    int w = tid >> 6;
    if (w > 0) v += ws[0];
    if (w > 1) v += ws[1];
    if (w > 2) v += ws[2];
    if (tid < nb) bsums[tid] = v;
}

__global__ __launch_bounds__(256) void scan3(int* __restrict__ data, const int* __restrict__ bsums, int n) {
    int i = blockIdx.x * 256 + threadIdx.x;
    if (i < n && blockIdx.x > 0) data[i] += bsums[blockIdx.x - 1];
}

// stores SRC NODE VALUE (not edge id) -> aggregate skips one indirection
__global__ __launch_bounds__(256) void fill_kernel(const int* __restrict__ src, const int* __restrict__ dst,
                                                   const int* __restrict__ off,
                                                   int* __restrict__ cursor, int* __restrict__ srcs) {
    int e = blockIdx.x * 256 + threadIdx.x;
    if (e < NE) {
        int d = dst[e];
        int pos = off[d] + atomicAdd(&cursor[d], 1);
        srcs[pos] = src[e];
    }
}

// ---- merged weight packing: W0,W1 -> GEMM B-frag order; w1 -> MLP B-frag order ----
__global__ __launch_bounds__(256) void pack_all(const float* __restrict__ W0, const float* __restrict__ W1,
                                                const float* __restrict__ w1,
                                                u16* __restrict__ w0pg, u16* __restrict__ w1pg,
                                                u16* __restrict__ w1p) {
    int id = blockIdx.x * 256 + threadIdx.x;
    if (id < 65536) {  // two GEMM weights, [128,256] each
        const float* W = (id < 32768) ? W0 : W1;
        u16* Wp = (id < 32768) ? w0pg : w1pg;
        int t = id & 32767;
        int k = t >> 8, n = t & 255;
        int kt = k >> 5, kk = k & 31, lg = kk >> 3, j = kk & 7;
        int nt = n >> 4, ln = n & 15;
        int lane = lg * 16 + ln;
        Wp[(((kt * 16 + nt) * 64) + lane) * 8 + j] = (u16)bfround(W[t]);
    } else if (id < 65536 + 49152) {  // w1 [384,128]
        int t = id - 65536;
        int k = t >> 7, n = t & 127;
        int kt = k >> 5, kk = k & 31, lg = kk >> 3, j = kk & 7;
        int ct = n >> 4, ln = n & 15;
        int lane = lg * 16 + ln;
        w1p[(((kt * 8 + ct) * 64) + lane) * 8 + j] = (u16)bfround(w1[t]);
    }
}

// ---- MFMA GEMM + attention-coef: C(bf16)[nrows,256] = A[nrows,128]@W ; el/er ----
// 1 block = 64 rows x 256 cols (BOTH heads). 4 waves x 16 rows. bf16 MFMA, fp32 acc.
template<bool ABF16>
__global__ __launch_bounds__(256) void gemm_mfma(const void* __restrict__ Av,
                                                 const u16* __restrict__ Wp,
                                                 const float* __restrict__ al,
                                                 const float* __restrict__ ar,
                                                 u16* __restrict__ C,
                                                 float* __restrict__ att, int nrows) {
    // sbuf: phase 1 = As[64][136] bf16; phase 2 = Cs[64][264] bf16 (coalesced store)
    __shared__ u16 sbuf[64 * 264];
    int rbase = blockIdx.x * 64;
    int tid = threadIdx.x;
    if (ABF16) {
        const uint4* A4 = (const uint4*)Av;
        for (int id = tid; id < 64 * 16; id += 256) {
            int r = id >> 4, seg = id & 15;
            int gr = rbase + r;
            uint4 v = make_uint4(0u, 0u, 0u, 0u);
            if (gr < nrows) v = A4[gr * 16 + seg];
            *(uint4*)&sbuf[r * 136 + seg * 8] = v;
        }
    } else {
        const float4* A4 = (const float4*)Av;
        for (int id = tid; id < 64 * 32; id += 256) {
            int r = id >> 5, seg = id & 31;
            int gr = rbase + r;
            float4 v = make_float4(0.f, 0.f, 0.f, 0.f);
            if (gr < nrows) v = A4[gr * 32 + seg];
            uint2 p;
            p.x = packbf(v.x, v.y);
            p.y = packbf(v.z, v.w);
            *(uint2*)&sbuf[r * 136 + seg * 4] = p;
        }
    }
    __syncthreads();
    int l = tid & 63, w = tid >> 6;
    int ln = l & 15, lg = l >> 4;
    f32x4 acc[16];
    #pragma unroll
    for (int nt = 0; nt < 16; ++nt) acc[nt] = (f32x4){0.f, 0.f, 0.f, 0.f};
    const short8* wp = (const short8*)Wp;
    const u16* arow = &sbuf[(w * 16 + ln) * 136 + lg * 8];
    #pragma unroll
    for (int kt = 0; kt < 4; ++kt) {
        short8 a = *(const short8*)&arow[kt * 32];
        #pragma unroll
        for (int nt = 0; nt < 16; ++nt) {
            short8 b = wp[(kt * 16 + nt) * 64 + l];
            acc[nt] = __builtin_amdgcn_mfma_f32_16x16x32_bf16(a, b, acc[nt], 0, 0, 0);
        }
    }
    // epilogue 1: attention coefficients from fp32 accumulators
    float alv[16], arv[16];
    #pragma unroll
    for (int nt = 0; nt < 16; ++nt) {
        alv[nt] = al[nt * 16 + ln];
        arv[nt] = ar[nt * 16 + ln];
    }
    #pragma unroll
    for (int r = 0; r < 4; ++r) {
        float pl0 = 0.f, pr0 = 0.f, pl1 = 0.f, pr1 = 0.f;
        #pragma unroll
        for (int nt = 0; nt < 8; ++nt) {
            pl0 += acc[nt][r] * alv[nt];
            pr0 += acc[nt][r] * arv[nt];
            pl1 += acc[nt + 8][r] * alv[nt + 8];
            pr1 += acc[nt + 8][r] * arv[nt + 8];
        }
        #pragma unroll
        for (int m = 1; m < 16; m <<= 1) {
            pl0 += __shfl_xor(pl0, m); pr0 += __shfl_xor(pr0, m);
            pl1 += __shfl_xor(pl1, m); pr1 += __shfl_xor(pr1, m);
        }
        int grow = rbase + w * 16 + lg * 4 + r;
        if (ln == 0 && grow < nrows) {
            att[grow * 4 + 0] = pl0;
            att[grow * 4 + 1] = pl1;
            att[grow * 4 + 2] = pr0;
            att[grow * 4 + 3] = pr1;
        }
    }
    __syncthreads();
    #pragma unroll
    for (int nt = 0; nt < 16; ++nt) {
        int col = nt * 16 + ln;
        #pragma unroll
        for (int r = 0; r < 4; ++r) {
            int row = w * 16 + lg * 4 + r;
            sbuf[row * 264 + col] = (u16)bfround(acc[nt][r]);
        }
    }
    __syncthreads();
    uint4* C4 = (uint4*)C;
    for (int id = tid; id < 64 * 32; id += 256) {
        int r = id >> 5, seg = id & 31;
        int gr = rbase + r;
        if (gr < nrows) C4[gr * 32 + seg] = *(uint4*)&sbuf[r * 264 + seg * 8];
    }
}

// ------- aggregate: 1 wave per node, register-only online softmax + shfl gather -------
// 128 thr = 2 nodes. Lane l<32: head0 features {4l..4l+3}; lane l+32: head1 same features.
__global__ __launch_bounds__(128) void aggregate(const u16* __restrict__ feat,
                                                 const int* __restrict__ off,
                                                 const int* __restrict__ srcs,
                                                 const float* __restrict__ att,
                                                 u16* __restrict__ hout) {
    int v = blockIdx.x * 2 + (threadIdx.x >> 6);
    int lane = threadIdx.x & 63;
    if (v >= NN) return;
    int s = off[v], deg = off[v + 1] - s;
    const float4* att4 = (const float4*)att;
    const uint2* featu2 = (const uint2*)feat;
    uint2* houtu2 = (uint2*)hout;
    float4 av = att4[v];
    float er0 = av.z, er1 = av.w;
    bool h0 = lane < 32;
    float m0 = -1e30f, m1 = -1e30f, d0 = 0.f, d1 = 0.f;
    float a0 = 0.f, a1 = 0.f, a2 = 0.f, a3 = 0.f;
    for (int cb = 0; cb < deg; cb += 64) {
        int k = cb + lane;
        int cn = min(64, deg - cb);
        int u = 0;
        float e0 = -1e30f, e1 = -1e30f;
        if (k < deg) {
            u = srcs[s + k];
            float4 au = att4[u];
            e0 = au.x + er0; e0 = e0 > 0.f ? e0 : 0.2f * e0;
            e1 = au.y + er1; e1 = e1 > 0.f ? e1 : 0.2f * e1;
        }
        float mc0 = e0, mc1 = e1;
        #pragma unroll
        for (int mm = 1; mm < 64; mm <<= 1) {
            mc0 = fmaxf(mc0, __shfl_xor(mc0, mm));
            mc1 = fmaxf(mc1, __shfl_xor(mc1, mm));
        }
        float m0n = fmaxf(m0, mc0), m1n = fmaxf(m1, mc1);
        float f0 = __expf(m0 - m0n), f1 = __expf(m1 - m1n);
        float w0 = (k < deg) ? __expf(e0 - m0n) : 0.f;
        float w1 = (k < deg) ? __expf(e1 - m1n) : 0.f;
        float s0 = w0, s1 = w1;
        #pragma unroll
        for (int mm = 1; mm < 64; mm <<= 1) {
            s0 += __shfl_xor(s0, mm);
            s1 += __shfl_xor(s1, mm);
        }
        d0 = d0 * f0 + s0;
        d1 = d1 * f1 + s1;
        float fa = h0 ? f0 : f1;
        a0 *= fa; a1 *= fa; a2 *= fa; a3 *= fa;
        m0 = m0n; m1 = m1n;
        int k2 = 0;
        for (; k2 + 4 <= cn; k2 += 4) {
            int uu0 = __shfl(u, k2), uu1 = __shfl(u, k2 + 1);
            int uu2 = __shfl(u, k2 + 2), uu3 = __shfl(u, k2 + 3);
            float wa0 = __shfl(w0, k2), wb0 = __shfl(w1, k2);
            float wa1 = __shfl(w0, k2 + 1), wb1 = __shfl(w1, k2 + 1);
            float wa2 = __shfl(w0, k2 + 2), wb2 = __shfl(w1, k2 + 2);
            float wa3 = __shfl(w0, k2 + 3), wb3 = __shfl(w1, k2 + 3);
            float wk0 = h0 ? wa0 : wb0, wk1 = h0 ? wa1 : wb1;
            float wk2 = h0 ? wa2 : wb2, wk3 = h0 ? wa3 : wb3;
            uint2 g0 = featu2[(size_t)uu0 * 64 + lane];
            uint2 g1 = featu2[(size_t)uu1 * 64 + lane];
            uint2 g2 = featu2[(size_t)uu2 * 64 + lane];
            uint2 g3 = featu2[(size_t)uu3 * 64 + lane];
            a0 += wk0 * bflo(g0.x) + wk1 * bflo(g1.x) + wk2 * bflo(g2.x) + wk3 * bflo(g3.x);
            a1 += wk0 * bfhi(g0.x) + wk1 * bfhi(g1.x) + wk2 * bfhi(g2.x) + wk3 * bfhi(g3.x);
            a2 += wk0 * bflo(g0.y) + wk1 * bflo(g1.y) + wk2 * bflo(g2.y) + wk3 * bflo(g3.y);
            a3 += wk0 * bfhi(g0.y) + wk1 * bfhi(g1.y) + wk2 * bfhi(g2.y) + wk3 * bfhi(g3.y);
        }
        for (; k2 < cn; ++k2) {
            int uu = __shfl(u, k2);
            float wa = __shfl(w0, k2), wb = __shfl(w1, k2);
            float wk = h0 ? wa : wb;
            uint2 g = featu2[(size_t)uu * 64 + lane];
            a0 += wk * bflo(g.x); a1 += wk * bfhi(g.x);
            a2 += wk * bflo(g.y); a3 += wk * bfhi(g.y);
        }
    }
    float dh = h0 ? d0 : d1;
    float r = 1.f / (dh + 1e-9f);
    float o0 = fmaxf(a0 * r, 0.f), o1 = fmaxf(a1 * r, 0.f);
    float o2 = fmaxf(a2 * r, 0.f), o3 = fmaxf(a3 * r, 0.f);
    float p0 = __shfl_xor(o0, 32), p1 = __shfl_xor(o1, 32);
    float p2 = __shfl_xor(o2, 32), p3 = __shfl_xor(o3, 32);
    if (h0) {
        uint2 q;
        q.x = packbf(0.5f * (o0 + p0), 0.5f * (o1 + p1));
        q.y = packbf(0.5f * (o2 + p2), 0.5f * (o3 + p3));
        houtu2[(size_t)v * 32 + lane] = q;
    }
}

// ---------------- fused pair MLP via MFMA ----------------
__global__ __launch_bounds__(256) void mlp_mfma(const u16* __restrict__ hf,
                                                const int* __restrict__ x1,
                                                const int* __restrict__ x2,
                                                const u16* __restrict__ w1p,
                                                const float* __restrict__ b1,
                                                const float* __restrict__ w2,
                                                const float* __restrict__ b2,
                                                float* __restrict__ out) {
    __shared__ u16 z[64][392];
    int pbase = blockIdx.x * 64;
    int tid = threadIdx.x;
    const uint4* hfu4 = (const uint4*)hf;
    for (int id = tid; id < 64 * 16; id += 256) {
        int p = id >> 4, seg = id & 15;
        int gp = pbase + p;
        uint4 v1 = make_uint4(0u, 0u, 0u, 0u), v2 = v1;
        if (gp < NPAIR) {
            v1 = hfu4[x1[gp] * 16 + seg];
            v2 = hfu4[x2[gp] * 16 + seg];
        }
        int c8 = seg << 3;
        *(uint4*)&z[p][c8] = v1;
        *(uint4*)&z[p][128 + c8] = v2;
        uint4 vd;
        vd.x = packbf(fabsf(bflo(v1.x) - bflo(v2.x)), fabsf(bfhi(v1.x) - bfhi(v2.x)));
        vd.y = packbf(fabsf(bflo(v1.y) - bflo(v2.y)), fabsf(bfhi(v1.y) - bfhi(v2.y)));
        vd.z = packbf(fabsf(bflo(v1.z) - bflo(v2.z)), fabsf(bfhi(v1.z) - bfhi(v2.z)));
        vd.w = packbf(fabsf(bflo(v1.w) - bflo(v2.w)), fabsf(bfhi(v1.w) - bfhi(v2.w)));
        *(uint4*)&z[p][256 + c8] = vd;
    }
    __syncthreads();
    int l = tid & 63, w = tid >> 6;
    int lg = l >> 4, ln = l & 15;
    f32x4 acc[8];
    #pragma unroll
    for (int ct = 0; ct < 8; ++ct) acc[ct] = (f32x4){0.f, 0.f, 0.f, 0.f};
    const short8* wp = (const short8*)w1p;
    const u16* zr = &z[w * 16 + ln][lg * 8];
    for (int kt = 0; kt < 12; ++kt) {
        short8 a = *(const short8*)&zr[kt * 32];
        #pragma unroll
        for (int ct = 0; ct < 8; ++ct) {
            short8 b = wp[(kt * 8 + ct) * 64 + l];
            acc[ct] = __builtin_amdgcn_mfma_f32_16x16x32_bf16(a, b, acc[ct], 0, 0, 0);
        }
    }
    float b1v[8], w20[8], w21[8];
    #pragma unroll
    for (int ct = 0; ct < 8; ++ct) {
        int n = ct * 16 + ln;
        b1v[ct] = b1[n];
        w20[ct] = w2[n * 2 + 0];
        w21[ct] = w2[n * 2 + 1];
    }
    float ob0 = b2[0], ob1 = b2[1];
    #pragma unroll
    for (int r = 0; r < 4; ++r) {
        float p0 = 0.f, p1 = 0.f;
        #pragma unroll
        for (int ct = 0; ct < 8; ++ct) {
            float zv = fmaxf(acc[ct][r] + b1v[ct], 0.f);
            p0 += zv * w20[ct]; p1 += zv * w21[ct];
        }
        #pragma unroll
        for (int m = 1; m < 16; m <<= 1) { p0 += __shfl_xor(p0, m); p1 += __shfl_xor(p1, m); }
        int gp = pbase + w * 16 + lg * 4 + r;
        if (ln == 0 && gp < NPAIR) {
            out[gp * 2 + 0] = p0 + ob0;
            out[gp * 2 + 1] = p1 + ob1;
        }
    }
}

extern "C" void kernel_launch(void* const* d_in, const int* in_sizes, int n_in,
                              void* d_out, int out_size, void* d_ws, size_t ws_size,
                              hipStream_t stream) {
    const int*   src = (const int*)d_in[0];
    const int*   dst = (const int*)d_in[1];
    const float* h   = (const float*)d_in[2];
    const int*   x1  = (const int*)d_in[3];
    const int*   x2  = (const int*)d_in[4];
    const float* W0  = (const float*)d_in[5];
    const float* al0 = (const float*)d_in[6];
    const float* ar0 = (const float*)d_in[7];
    const float* W1  = (const float*)d_in[8];
    const float* al1 = (const float*)d_in[9];
    const float* ar1 = (const float*)d_in[10];
    const float* w1  = (const float*)d_in[11];
    const float* b1  = (const float*)d_in[12];
    const float* w2  = (const float*)d_in[13];
    const float* b2  = (const float*)d_in[14];
    float* out = (float*)d_out;

    char* ws = (char*)d_ws;
    size_t o = 0;
    auto alloc = [&](size_t bytes) { size_t r = o; o = (o + bytes + 255) & ~255UL; return r; };
    int* off    = (int*)(ws + alloc((NN + 1) * sizeof(int)));
    int* cursor = (int*)(ws + alloc(NN * sizeof(int)));
    int* bsums  = (int*)(ws + alloc(256 * sizeof(int)));
    int* srcs   = (int*)(ws + alloc(NE * sizeof(int)));
    float* att  = (float*)(ws + alloc((size_t)NN * 4 * sizeof(float)));
    u16* feat   = (u16*)(ws + alloc((size_t)NN * 256 * sizeof(u16)));
    u16* hb0    = (u16*)(ws + alloc((size_t)NN * 128 * sizeof(u16)));
    u16* hb1    = (u16*)(ws + alloc((size_t)NN * 128 * sizeof(u16)));
    u16* w1p    = (u16*)(ws + alloc((size_t)384 * 128 * sizeof(u16)));
    u16* w0pg   = (u16*)(ws + alloc((size_t)128 * 256 * sizeof(u16)));
    u16* w1pg   = (u16*)(ws + alloc((size_t)128 * 256 * sizeof(u16)));

    hipMemsetAsync(off, 0, (NN + 1) * sizeof(int), stream);
    hipMemsetAsync(cursor, 0, NN * sizeof(int), stream);

    int eblocks = (NE + 255) / 256;
    int nscan = NN + 1;
    int nb = (nscan + 255) / 256;
    count_kernel<<<eblocks, 256, 0, stream>>>(dst, off);
    scan1<<<nb, 256, 0, stream>>>(off, bsums, nscan);
    scan2<<<1, 256, 0, stream>>>(bsums, nb);
    scan3<<<nb, 256, 0, stream>>>(off, bsums, nscan);
    fill_kernel<<<eblocks, 256, 0, stream>>>(src, dst, off, cursor, srcs);
    pack_all<<<448, 256, 0, stream>>>(W0, W1, w1, w0pg, w1pg, w1p);

    int gblocks = (NN + 63) / 64;
    // layer 0 (A fp32)
    gemm_mfma<false><<<gblocks, 256, 0, stream>>>((const void*)h, w0pg, al0, ar0, feat, att, NN);
    aggregate<<<(NN + 1) / 2, 128, 0, stream>>>(feat, off, srcs, att, hb0);
    // layer 1 (A bf16)
    gemm_mfma<true><<<gblocks, 256, 0, stream>>>((const void*)hb0, w1pg, al1, ar1, feat, att, NN);
    aggregate<<<(NN + 1) / 2, 128, 0, stream>>>(feat, off, srcs, att, hb1);
    // pair MLP (MFMA)
    mlp_mfma<<<(NPAIR + 63) / 64, 256, 0, stream>>>(hb1, x1, x2, w1p, b1, w2, b2, out);
}